// Round 2
// 1012.121 us; speedup vs baseline: 1.3453x; 1.3453x over previous
//
#include <hip/hip_runtime.h>
#include <hip/hip_bf16.h>
#include <stdint.h>

// ---------------------------------------------------------------------------
#define LSEQ 768
#define DM   256
#define NH   8
#define DK   32
#define DFF  1024
#define NLAYER 8
#define NDD  1535
// ---------------------------------------------------------------------------

typedef __attribute__((ext_vector_type(8))) short  bf16x8;
typedef __attribute__((ext_vector_type(4))) float  f32x4;

__device__ __forceinline__ unsigned short f2bf(float f) {
  unsigned u = __float_as_uint(f);
  u += 0x7fffu + ((u >> 16) & 1u);       // RNE
  return (unsigned short)(u >> 16);
}
__device__ __forceinline__ float bf2f(unsigned short h) {
  return __uint_as_float((unsigned)h << 16);
}
__device__ __forceinline__ unsigned pk2(float a, float b) {
  __hip_bfloat162 h = __float22bfloat162_rn(make_float2(a, b));
  union { __hip_bfloat162 h; unsigned u; } c; c.h = h;
  return c.u;
}
// split x,y into packed-bf16 hi word + lo (residual) word
__device__ __forceinline__ void split2(float x, float y,
                                       unsigned& hi, unsigned& lo) {
  unsigned short hx = f2bf(x), hy = f2bf(y);
  unsigned short lx = f2bf(x - bf2f(hx)), ly = f2bf(y - bf2f(hy));
  hi = (unsigned)hx | ((unsigned)hy << 16);
  lo = (unsigned)lx | ((unsigned)ly << 16);
}
__device__ __forceinline__ int bucket_of(int dd) {
  int rel = dd - 767;
  int ret = rel < 0 ? 32 : 0;
  int arp = rel < 0 ? -rel : rel;
  if (arp < 16) return ret + arp;
  const float lr = 2.772588722239781f;   // float(np.log(16))
  float val = logf((float)arp * 0.0625f) / lr * 16.0f;
  int vi = 16 + (int)val;
  return ret + (vi < 31 ? vi : 31);
}

// compensated product: acc += Ah*Bl + Al*Bh + Ah*Bh  (fp32 accumulate)
__device__ __forceinline__ f32x4 mfma3(bf16x8 ah, bf16x8 al,
                                       const unsigned short* ph,
                                       const unsigned short* pl, f32x4 ac) {
  bf16x8 bh = *(const bf16x8*)ph;
  bf16x8 bl = *(const bf16x8*)pl;
  ac = __builtin_amdgcn_mfma_f32_16x16x32_bf16(ah, bl, ac, 0, 0, 0);
  ac = __builtin_amdgcn_mfma_f32_16x16x32_bf16(al, bh, ac, 0, 0, 0);
  ac = __builtin_amdgcn_mfma_f32_16x16x32_bf16(ah, bh, ac, 0, 0, 0);
  return ac;
}

// ---------------------------------------------------------------------------
// MFMA B-fragment packers (hi/lo split): row-major [K][N] fp32 ->
// [K/32][N/16][lane][8] bf16 in two arrays (hi, residual-lo).
__device__ __forceinline__ void pack8s(unsigned short* dh, unsigned short* dl,
                                       int id, const float* src, int N, int G) {
  int lane = (id >> 3) & 63;
  int rem = id >> 9;
  int g = rem % G, kc = rem / G;
  int kb = kc * 32 + ((lane >> 4) << 3);
  int n = g * 16 + (lane & 15);
  union { unsigned short s[8]; uint4 v; } H, L;
  #pragma unroll
  for (int e = 0; e < 8; ++e) {
    float w = src[(size_t)(kb + e) * N + n];
    unsigned short h = f2bf(w);
    H.s[e] = h;
    L.s[e] = f2bf(w - bf2f(h));
  }
  *(uint4*)(dh + id) = H.v;
  *(uint4*)(dl + id) = L.v;
}

// N-concat of up to 3 [K][256] matrices (qkv: G=48, pair q/k: G=32)
__device__ __forceinline__ void pack8s_cat(unsigned short* dh, unsigned short* dl,
                                           int id, const float* s0,
                                           const float* s1, const float* s2,
                                           int G) {
  int lane = (id >> 3) & 63;
  int rem = id >> 9;
  int g = rem % G, kc = rem / G;
  int kb = kc * 32 + ((lane >> 4) << 3);
  int n = g * 16 + (lane & 15);
  const float* sp = n < 256 ? s0 : (n < 512 ? s1 : s2);
  int nn = n & 255;
  union { unsigned short s[8]; uint4 v; } H, L;
  #pragma unroll
  for (int e = 0; e < 8; ++e) {
    float w = sp[(size_t)(kb + e) * 256 + nn];
    unsigned short h = f2bf(w);
    H.s[e] = h;
    L.s[e] = f2bf(w - bf2f(h));
  }
  *(uint4*)(dh + id) = H.v;
  *(uint4*)(dl + id) = L.v;
}

// ---------------------------------------------------------------------------
// Legacy 64x64 GEMM tile (k_prep only; plain caching, gather variants).
// LDS from smc: As 2x32x68 @0, Bs @17408, stat @34816, red @35328 -> 37376.
template <int LN, int GR>
__device__ void gemm_tile(const float* gsrc, const int* seqIdx,
                          const float* B, const float* bias, float* C,
                          const float* lns, const float* lnb,
                          int M, int K, int N, int m0, int n0, char* smc) {
  float (*As)[32][68] = (float (*)[32][68])smc;
  float (*Bs)[32][68] = (float (*)[32][68])(smc + 17408);
  float (*stat)[2]    = (float (*)[2])(smc + 34816);
  float (*red)[8]     = (float (*)[8])(smc + 35328);

  int t = threadIdx.x;
  int arow = t >> 2, akq = (t & 3) * 8;
  int mg = m0 + arow;
  int mgc = mg < M ? mg : M - 1;
  const float* Ar = (GR == 1) ? (gsrc + (size_t)seqIdx[mgc] * K)
                              : (gsrc + (size_t)bucket_of(mgc) * K);
  float mean = 0.f, rstd = 0.f;
  if (LN) {
    int lq = t & 3;
    float s = 0.f, s2 = 0.f;
    const float* p = Ar + lq * 64;
    #pragma unroll
    for (int c = 0; c < 64; c += 4) {
      float4 v = *(const float4*)(p + c);
      s  += v.x + v.y + v.z + v.w;
      s2 += v.x * v.x + v.y * v.y + v.z * v.z + v.w * v.w;
    }
    red[arow][lq] = s; red[arow][lq + 4] = s2;
    __syncthreads();
    if (lq == 0) {
      float sm = red[arow][0] + red[arow][1] + red[arow][2] + red[arow][3];
      float sq = red[arow][4] + red[arow][5] + red[arow][6] + red[arow][7];
      float m = sm * (1.f / 256.f);
      float v = sq * (1.f / 256.f) - m * m;
      stat[arow][0] = m;
      stat[arow][1] = rsqrtf(v + 1e-5f);
    }
    __syncthreads();
    mean = stat[arow][0]; rstd = stat[arow][1];
  }

  int bkr = t >> 3, bn8 = (t & 7) * 8;
  int ty = t >> 4, tx = t & 15;
  float acc[4][4] = {};
  int nk = K >> 5;

  for (int kt = 0; kt < nk; ++kt) {
    int k0 = kt << 5;
    float4 a0 = *(const float4*)(Ar + k0 + akq);
    float4 a1 = *(const float4*)(Ar + k0 + akq + 4);
    if (LN) {
      float4 ls0 = *(const float4*)(lns + k0 + akq), ls1 = *(const float4*)(lns + k0 + akq + 4);
      float4 lb0 = *(const float4*)(lnb + k0 + akq), lb1 = *(const float4*)(lnb + k0 + akq + 4);
      a0.x=(a0.x-mean)*rstd*ls0.x+lb0.x; a0.y=(a0.y-mean)*rstd*ls0.y+lb0.y;
      a0.z=(a0.z-mean)*rstd*ls0.z+lb0.z; a0.w=(a0.w-mean)*rstd*ls0.w+lb0.w;
      a1.x=(a1.x-mean)*rstd*ls1.x+lb1.x; a1.y=(a1.y-mean)*rstd*ls1.y+lb1.y;
      a1.z=(a1.z-mean)*rstd*ls1.z+lb1.z; a1.w=(a1.w-mean)*rstd*ls1.w+lb1.w;
    }
    int cur = kt & 1;
    As[cur][akq+0][arow]=a0.x; As[cur][akq+1][arow]=a0.y; As[cur][akq+2][arow]=a0.z; As[cur][akq+3][arow]=a0.w;
    As[cur][akq+4][arow]=a1.x; As[cur][akq+5][arow]=a1.y; As[cur][akq+6][arow]=a1.z; As[cur][akq+7][arow]=a1.w;
    *(float4*)&Bs[cur][bkr][bn8] = *(const float4*)(B + (size_t)(k0 + bkr) * N + n0 + bn8);
    *(float4*)&Bs[cur][bkr][bn8+4] = *(const float4*)(B + (size_t)(k0 + bkr) * N + n0 + bn8 + 4);
    __syncthreads();
    #pragma unroll 8
    for (int kk = 0; kk < 32; ++kk) {
      float4 a = *(float4*)&As[cur][kk][ty * 4];
      float4 b = *(float4*)&Bs[cur][kk][tx * 4];
      acc[0][0]=fmaf(a.x,b.x,acc[0][0]); acc[0][1]=fmaf(a.x,b.y,acc[0][1]);
      acc[0][2]=fmaf(a.x,b.z,acc[0][2]); acc[0][3]=fmaf(a.x,b.w,acc[0][3]);
      acc[1][0]=fmaf(a.y,b.x,acc[1][0]); acc[1][1]=fmaf(a.y,b.y,acc[1][1]);
      acc[1][2]=fmaf(a.y,b.z,acc[1][2]); acc[1][3]=fmaf(a.y,b.w,acc[1][3]);
      acc[2][0]=fmaf(a.z,b.x,acc[2][0]); acc[2][1]=fmaf(a.z,b.y,acc[2][1]);
      acc[2][2]=fmaf(a.z,b.z,acc[2][2]); acc[2][3]=fmaf(a.z,b.w,acc[2][3]);
      acc[3][0]=fmaf(a.w,b.x,acc[3][0]); acc[3][1]=fmaf(a.w,b.y,acc[3][1]);
      acc[3][2]=fmaf(a.w,b.z,acc[3][2]); acc[3][3]=fmaf(a.w,b.w,acc[3][3]);
    }
    __syncthreads();
  }

  #pragma unroll
  for (int u = 0; u < 4; ++u) {
    int m = m0 + ty * 4 + u;
    if (m < M) {
      int n = n0 + tx * 4;
      float4 val = make_float4(acc[u][0], acc[u][1], acc[u][2], acc[u][3]);
      if (bias) {
        float4 bv = *(const float4*)(bias + n);
        val.x += bv.x; val.y += bv.y; val.z += bv.z; val.w += bv.w;
      }
      *(float4*)(C + (size_t)m * N + n) = val;
    }
  }
}

// ---------------------------------------------------------------------------
// Prep: RB gemm + qkv layer0 + embed + abias + W1p pack + MFMA weight packs.
__global__ __launch_bounds__(256, 2) void k_prep(
    const int* __restrict__ seq, const float* __restrict__ tok_emb,
    const float* __restrict__ rp_emb,
    const float* __restrict__ wq, const float* __restrict__ wk,
    const float* __restrict__ wv, const float* __restrict__ wo,
    const float* __restrict__ ffn_w1, const float* __restrict__ ffn_w2,
    const float* __restrict__ ln1s0, const float* __restrict__ ln1b0,
    const float* __restrict__ pair_rp, const float* __restrict__ cls_w1,
    const float* __restrict__ cls_b1,
    const float* __restrict__ pair_q_w, const float* __restrict__ pair_k_w,
    float* x0, float* q0, float* k0, float* v0, float* RB,
    unsigned short* W1p, float* abias,
    unsigned short* Woph, unsigned short* Wopl,
    unsigned short* W1ph, unsigned short* W1pl,
    unsigned short* W2ph, unsigned short* W2pl,
    unsigned short* Wqkvh, unsigned short* Wqkvl,
    unsigned short* Wpairh, unsigned short* Wpairl) {
  __shared__ __align__(16) char sm[37376];
  int b = blockIdx.x, t = threadIdx.x;
  if (b < 96) {
    int m0 = (b % 24) * 64, n0 = (b / 24) * 64;
    gemm_tile<0,2>(pair_rp, nullptr, cls_w1, cls_b1, RB,
                   nullptr, nullptr, NDD, 256, 256, m0, n0, sm);
  } else if (b < 240) {
    int u = b - 96;
    int n0g = (u % 12) * 64, m0 = (u / 12) * 64;
    int bi = n0g >> 8, n0 = n0g & 255;
    const float* B = bi == 0 ? wq : (bi == 1 ? wk : wv);
    float* C = bi == 0 ? q0 : (bi == 1 ? k0 : v0);
    gemm_tile<1,1>(tok_emb, seq, B, nullptr, C,
                   ln1s0, ln1b0, LSEQ, 256, 256, m0, n0, sm);
  } else if (b < 432) {
    int row = (b - 240) * 4 + (t >> 6), c = (t & 63) * 4;
    *(float4*)(x0 + (size_t)row * DM + c) =
        *(const float4*)(tok_emb + (size_t)seq[row] * DM + c);
  } else if (b < 438) {
    int dd = (b - 432) * 256 + t;
    if (dd < NDD) {
      int bk = bucket_of(dd);
      #pragma unroll
      for (int h = 0; h < NH; ++h) abias[dd * 8 + h] = rp_emb[bk * 8 + h];
    }
  } else if (b < 502) {
    int base = (b - 438) * 1024 + t * 4;
    #pragma unroll
    for (int uu = 0; uu < 4; ++uu) {
      int id = base + uu;
      int e = id & 7, lane = (id >> 3) & 63, g = (id >> 9) & 15, kc = id >> 13;
      int kg = kc * 32 + (lane >> 4) * 8 + e;
      int n  = g * 16 + (lane & 15);
      W1p[id] = f2bf(cls_w1[(size_t)kg * 256 + n]);
    }
  } else {
    // MFMA weight packing (hi/lo): 3136 blocks x 2048 elems
    int u = (b - 502) * 2048 + t * 8;
    if (u < 524288) {                       // wo: 8 x [256][256], G=16
      int layer = u >> 16, id = u & 65535;
      pack8s(Woph + ((size_t)layer << 16), Wopl + ((size_t)layer << 16),
             id, wo + ((size_t)layer << 16), 256, 16);
    } else if (u < 2621440) {               // ffn_w1: 8 x [256][1024], G=64
      int v2 = u - 524288; int layer = v2 >> 18, id = v2 & 262143;
      pack8s(W1ph + ((size_t)layer << 18), W1pl + ((size_t)layer << 18),
             id, ffn_w1 + ((size_t)layer << 18), 1024, 64);
    } else if (u < 4718592) {               // ffn_w2: 8 x [1024][256], G=16
      int v2 = u - 2621440; int layer = v2 >> 18, id = v2 & 262143;
      pack8s(W2ph + ((size_t)layer << 18), W2pl + ((size_t)layer << 18),
             id, ffn_w2 + ((size_t)layer << 18), 256, 16);
    } else if (u < 6291456) {               // qkv concat: 8 x [256][768], G=48
      int v2 = u - 4718592; int layer = v2 / 196608, id = v2 - layer * 196608;
      pack8s_cat(Wqkvh + (size_t)layer * 196608, Wqkvl + (size_t)layer * 196608,
                 id, wq + ((size_t)layer << 16), wk + ((size_t)layer << 16),
                 wv + ((size_t)layer << 16), 48);
    } else {                                // pair q/k concat: [256][512], G=32
      int id = u - 6291456;
      pack8s_cat(Wpairh, Wpairl, id, pair_q_w, pair_k_w, pair_k_w, 32);
    }
  }
}

// ---------------------------------------------------------------------------
// Attention (validated round 7): 16 q-rows x 1 head per block.
#define ATTN_SMEM 72960

__global__ __launch_bounds__(256, 2) void k_attn2(
    const float* __restrict__ q, const float* __restrict__ k,
    const float* __restrict__ v, const float* __restrict__ abias,
    float* __restrict__ o) {
  extern __shared__ char sm[];
  float* S  = (float*)sm;
  float* KV = (float*)(sm + 49664);
  float* QS = (float*)(sm + 66560);
  float* BS = (float*)(sm + 68672);
  float (*red)[16] = (float (*)[16])(sm + 71808);
  float* mrow = (float*)(sm + 72832);
  float* linv = (float*)(sm + 72896);

  int i0 = blockIdx.x * 16, h = blockIdx.y, hc = h * DK;
  int t = threadIdx.x;

  for (int u = t; u < 783; u += 256)
    BS[u] = abias[(size_t)(i0 + u) * 8 + h];
  {
    int r = t >> 4, c = t & 15;
    const float inv = 0.17677669529663687f;   // 1/sqrt(32)
    QS[r * 33 + c]      = q[(size_t)(i0 + r) * DM + hc + c] * inv;
    QS[r * 33 + c + 16] = q[(size_t)(i0 + r) * DM + hc + c + 16] * inv;
  }

  int kx = t & 31, ry = t >> 5;
  int key = t >> 1, half = t & 1;

  for (int cc = 0; cc < 6; ++cc) {
    const float* kp = k + (size_t)(cc * 128 + key) * DM + hc + half * 16;
    float4 L0 = *(const float4*)(kp);
    float4 L1 = *(const float4*)(kp + 4);
    float4 L2 = *(const float4*)(kp + 8);
    float4 L3 = *(const float4*)(kp + 12);
    __syncthreads();
    int cb = half * 16;
    KV[(cb+ 0)*132+key]=L0.x; KV[(cb+ 1)*132+key]=L0.y; KV[(cb+ 2)*132+key]=L0.z; KV[(cb+ 3)*132+key]=L0.w;
    KV[(cb+ 4)*132+key]=L1.x; KV[(cb+ 5)*132+key]=L1.y; KV[(cb+ 6)*132+key]=L1.z; KV[(cb+ 7)*132+key]=L1.w;
    KV[(cb+ 8)*132+key]=L2.x; KV[(cb+ 9)*132+key]=L2.y; KV[(cb+10)*132+key]=L2.z; KV[(cb+11)*132+key]=L2.w;
    KV[(cb+12)*132+key]=L3.x; KV[(cb+13)*132+key]=L3.y; KV[(cb+14)*132+key]=L3.z; KV[(cb+15)*132+key]=L3.w;
    __syncthreads();

    float s0x=0,s0y=0,s0z=0,s0w=0, s1x=0,s1y=0,s1z=0,s1w=0;
    #pragma unroll
    for (int kk = 0; kk < 32; ++kk) {
      float q0 = QS[(ry*2    )*33 + kk];
      float q1 = QS[(ry*2 + 1)*33 + kk];
      float4 kv4 = *(const float4*)&KV[kk*132 + kx*4];
      s0x = fmaf(q0, kv4.x, s0x); s0y = fmaf(q0, kv4.y, s0y);
      s0z = fmaf(q0, kv4.z, s0z); s0w = fmaf(q0, kv4.w, s0w);
      s1x = fmaf(q1, kv4.x, s1x); s1y = fmaf(q1, kv4.y, s1y);
      s1z = fmaf(q1, kv4.z, s1z); s1w = fmaf(q1, kv4.w, s1w);
    }
    int jb = cc * 128 + kx * 4;
    int r0 = ry * 2, r1 = r0 + 1;
    S[r0*776 + jb+0] = s0x + BS[r0 + 767 - (jb+0)];
    S[r0*776 + jb+1] = s0y + BS[r0 + 767 - (jb+1)];
    S[r0*776 + jb+2] = s0z + BS[r0 + 767 - (jb+2)];
    S[r0*776 + jb+3] = s0w + BS[r0 + 767 - (jb+3)];
    S[r1*776 + jb+0] = s1x + BS[r1 + 767 - (jb+0)];
    S[r1*776 + jb+1] = s1y + BS[r1 + 767 - (jb+1)];
    S[r1*776 + jb+2] = s1z + BS[r1 + 767 - (jb+2)];
    S[r1*776 + jb+3] = s1w + BS[r1 + 767 - (jb+3)];
  }
  __syncthreads();

  {
    int ti = t >> 4, tj = t & 15;
    float mx = -1e30f;
    for (int jc = 0; jc < 48; ++jc)
      mx = fmaxf(mx, S[ti*776 + jc*16 + tj]);
    red[ti][tj] = mx;
    __syncthreads();
    if (tj == 0) {
      float m2 = red[ti][0];
      #pragma unroll
      for (int u = 1; u < 16; ++u) m2 = fmaxf(m2, red[ti][u]);
      mrow[ti] = m2;
    }
    __syncthreads();
    float m2 = mrow[ti];
    float sum = 0.f;
    for (int jc = 0; jc < 48; ++jc) {
      int j = jc*16 + tj;
      float e = __expf(S[ti*776 + j] - m2);
      S[ti*776 + j] = e;
      sum += e;
    }
    red[ti][tj] = sum;
    __syncthreads();
    if (tj == 0) {
      float s2 = 0.f;
      #pragma unroll
      for (int u = 0; u < 16; ++u) s2 += red[ti][u];
      linv[ti] = 1.f / s2;
    }
  }

  int cp = t & 15, jg = t >> 4;
  int c0 = cp * 2, c1 = c0 + 1;
  float oc0[16] = {}, oc1[16] = {};
  for (int cc = 0; cc < 6; ++cc) {
    const float* vp = v + (size_t)(cc * 128 + key) * DM + hc + half * 16;
    float4 L0 = *(const float4*)(vp);
    float4 L1 = *(const float4*)(vp + 4);
    float4 L2 = *(const float4*)(vp + 8);
    float4 L3 = *(const float4*)(vp + 12);
    __syncthreads();
    int cb = half * 16;
    KV[(cb+ 0)*132+key]=L0.x; KV[(cb+ 1)*132+key]=L0.y; KV[(cb+ 2)*132+key]=L0.z; KV[(cb+ 3)*132+key]=L0.w;
    KV[(cb+ 4)*132+key]=L1.x; KV[(cb+ 5)*132+key]=L1.y; KV[(cb+ 6)*132+key]=L1.z; KV[(cb+ 7)*132+key]=L1.w;
    KV[(cb+ 8)*132+key]=L2.x; KV[(cb+ 9)*132+key]=L2.y; KV[(cb+10)*132+key]=L2.z; KV[(cb+11)*132+key]=L2.w;
    KV[(cb+12)*132+key]=L3.x; KV[(cb+13)*132+key]=L3.y; KV[(cb+14)*132+key]=L3.z; KV[(cb+15)*132+key]=L3.w;
    __syncthreads();

    #pragma unroll
    for (int jj2 = 0; jj2 < 2; ++jj2) {
      int jb = jg * 8 + jj2 * 4;
      float4 vA = *(const float4*)&KV[c0*132 + jb];
      float4 vB = *(const float4*)&KV[c1*132 + jb];
      #pragma unroll
      for (int r = 0; r < 16; ++r) {
        float4 sv = *(const float4*)&S[r*776 + cc*128 + jb];
        oc0[r] += sv.x*vA.x + sv.y*vA.y + sv.z*vA.z + sv.w*vA.w;
        oc1[r] += sv.x*vB.x + sv.y*vB.y + sv.z*vB.z + sv.w*vB.w;
      }
    }
  }

  #pragma unroll
  for (int h2 = 0; h2 < 2; ++h2) {
    __syncthreads();
    #pragma unroll
    for (int r = 0; r < 8; ++r) {
      KV[(jg*8 + r)*32 + c0] = oc0[h2*8 + r];
      KV[(jg*8 + r)*32 + c1] = oc1[h2*8 + r];
    }
    __syncthreads();
    int r = t >> 5, c = t & 31;
    float s = 0.f;
    #pragma unroll
    for (int jgg = 0; jgg < 16; ++jgg) s += KV[(jgg*8 + r)*32 + c];
    o[(size_t)(i0 + h2*8 + r) * DM + hc + c] = s * linv[h2*8 + r];
  }
}

// ---------------------------------------------------------------------------
// MFMA fused layer tail (split-bf16 compensated): wo+res -> LN2 -> ffn1(gelu)
// -> ffn2+res -> LN1next -> qkv (or pair proj). 48 blocks x 512 threads,
// 16 rows/block. Every GEMM = 3 MFMAs on hi/lo operand splits (~fp32 acc).
#define TAIL_SMEM 99584

struct TB {
  const float* o; const float* xin;
  const unsigned short* woph; const unsigned short* wopl;
  const float* ln2s; const float* ln2b;
  const unsigned short* w1ph; const unsigned short* w1pl; const float* fb1;
  const unsigned short* w2ph; const unsigned short* w2pl; const float* fb2;
  const unsigned short* wnph; const unsigned short* wnpl;
  const float* lns; const float* lnb;
  const float* nb0; const float* nb1;
  float *qo, *ko, *vo, *xo;
};

// LN over 16 rows x 256 cols: 32 threads/row, shuffle-reduce, split out.
__device__ __forceinline__ void ln16(float (*Xf)[260],
                                     unsigned short (*Abh)[264],
                                     unsigned short (*Abl)[264],
                                     const float* s, const float* b, int t) {
  int r = t >> 5, j = t & 31;
  int c0 = j * 8;
  float x[8];
  float s1 = 0.f, s2 = 0.f;
  #pragma unroll
  for (int u = 0; u < 8; ++u) {
    x[u] = Xf[r][c0 + u];
    s1 += x[u]; s2 += x[u] * x[u];
  }
  #pragma unroll
  for (int m = 1; m < 32; m <<= 1) {
    s1 += __shfl_xor(s1, m);
    s2 += __shfl_xor(s2, m);
  }
  float mean = s1 * (1.f / 256.f);
  float var  = s2 * (1.f / 256.f) - mean * mean;
  float rs = rsqrtf(var + 1e-5f);
  unsigned hh[4], ll[4];
  #pragma unroll
  for (int p = 0; p < 4; ++p) {
    float h0 = (x[p*2]   - mean) * rs * s[c0 + p*2]   + b[c0 + p*2];
    float h1 = (x[p*2+1] - mean) * rs * s[c0 + p*2+1] + b[c0 + p*2+1];
    split2(h0, h1, hh[p], ll[p]);
  }
  *(uint4*)&Abh[r][c0] = make_uint4(hh[0], hh[1], hh[2], hh[3]);
  *(uint4*)&Abl[r][c0] = make_uint4(ll[0], ll[1], ll[2], ll[3]);
}

template <int LAST>
__global__ __launch_bounds__(512, 1) void k_tail2(TB a) {
  extern __shared__ char smt[];
  float (*Xf)[260]           = (float (*)[260])smt;                    // 16640
  unsigned short (*Abh)[264] = (unsigned short (*)[264])(smt + 16640); //  8448
  unsigned short (*Abl)[264] = (unsigned short (*)[264])(smt + 25088); //  8448
  unsigned short (*Fbh)[1032] = (unsigned short (*)[1032])(smt + 33536); // 33024
  unsigned short (*Fbl)[1032] = (unsigned short (*)[1032])(smt + 66560); // 33024

  int t = threadIdx.x;
  int i0 = blockIdx.x * 16;
  int w = t >> 6, l = t & 63;
  int lr = l & 15, lq = l >> 4;

  // ---- stage 0: O -> Abh/Abl (split bf16), xin -> Xf ----
  {
    int row = t >> 5, col = (t & 31) * 8;
    const float* op = a.o + (size_t)(i0 + row) * DM + col;
    float4 v0 = *(const float4*)op, v1 = *(const float4*)(op + 4);
    unsigned hh[4], ll[4];
    split2(v0.x, v0.y, hh[0], ll[0]);
    split2(v0.z, v0.w, hh[1], ll[1]);
    split2(v1.x, v1.y, hh[2], ll[2]);
    split2(v1.z, v1.w, hh[3], ll[3]);
    *(uint4*)&Abh[row][col] = make_uint4(hh[0], hh[1], hh[2], hh[3]);
    *(uint4*)&Abl[row][col] = make_uint4(ll[0], ll[1], ll[2], ll[3]);
    const float* xp = a.xin + (size_t)(i0 + row) * DM + col;
    *(float4*)&Xf[row][col]     = *(const float4*)xp;
    *(float4*)&Xf[row][col + 4] = *(const float4*)(xp + 4);
  }
  __syncthreads();

  bf16x8 af[8], afl[8];
  #pragma unroll
  for (int kc = 0; kc < 8; ++kc) {
    af[kc]  = *(const bf16x8*)&Abh[lr][kc * 32 + lq * 8];
    afl[kc] = *(const bf16x8*)&Abl[lr][kc * 32 + lq * 8];
  }

  // ---- stage 1: X1 = xin + O@Wo (wave w owns n-cols [w*32, w*32+31]) ----
  #pragma unroll
  for (int gi = 0; gi < 2; ++gi) {
    int g = w * 2 + gi;
    f32x4 ac = {0.f, 0.f, 0.f, 0.f};
    #pragma unroll
    for (int kc = 0; kc < 8; ++kc) {
      int off = ((kc * 16 + g) << 9) + (l << 3);
      ac = mfma3(af[kc], afl[kc], a.woph + off, a.wopl + off, ac);
    }
    int n = g * 16 + lr;
    #pragma unroll
    for (int r = 0; r < 4; ++r)
      Xf[lq * 4 + r][n] += ac[r];
  }
  __syncthreads();

  // ---- LN2 -> Abh/Abl ----
  ln16(Xf, Abh, Abl, a.ln2s, a.ln2b, t);
  __syncthreads();

  #pragma unroll
  for (int kc = 0; kc < 8; ++kc) {
    af[kc]  = *(const bf16x8*)&Abh[lr][kc * 32 + lq * 8];
    afl[kc] = *(const bf16x8*)&Abl[lr][kc * 32 + lq * 8];
  }

  // ---- stage 3: ffn1 + gelu -> Fbh/Fbl (wave w owns n-cols [w*128, +127]) ----
  #pragma unroll 2
  for (int gi = 0; gi < 8; ++gi) {
    int g = w * 8 + gi;
    f32x4 ac = {0.f, 0.f, 0.f, 0.f};
    #pragma unroll
    for (int kc = 0; kc < 8; ++kc) {
      int off = ((kc * 64 + g) << 9) + (l << 3);
      ac = mfma3(af[kc], afl[kc], a.w1ph + off, a.w1pl + off, ac);
    }
    int n = g * 16 + lr;
    float bb1 = a.fb1[n];
    #pragma unroll
    for (int r = 0; r < 4; ++r) {
      float v = ac[r] + bb1;
      v = 0.5f * v * (1.f + erff(v * 0.70710678118654752f));
      unsigned short h = f2bf(v);
      Fbh[lq * 4 + r][n] = h;
      Fbl[lq * 4 + r][n] = f2bf(v - bf2f(h));
    }
  }
  __syncthreads();

  // ---- stage 4: X2 = X1 + F@W2 + b2, store xo ----
  {
    f32x4 ac2[2] = {{0.f,0.f,0.f,0.f}, {0.f,0.f,0.f,0.f}};
    #pragma unroll 4
    for (int kc = 0; kc < 32; ++kc) {
      bf16x8 a4h = *(const bf16x8*)&Fbh[lr][kc * 32 + lq * 8];
      bf16x8 a4l = *(const bf16x8*)&Fbl[lr][kc * 32 + lq * 8];
      #pragma unroll
      for (int gi = 0; gi < 2; ++gi) {
        int g = w * 2 + gi;
        int off = ((kc * 16 + g) << 9) + (l << 3);
        ac2[gi] = mfma3(a4h, a4l, a.w2ph + off, a.w2pl + off, ac2[gi]);
      }
    }
    #pragma unroll
    for (int gi = 0; gi < 2; ++gi) {
      int n = (w * 2 + gi) * 16 + lr;
      float bb2 = a.fb2[n];
      #pragma unroll
      for (int r = 0; r < 4; ++r) {
        int rr = lq * 4 + r;
        float x2 = Xf[rr][n] + ac2[gi][r] + bb2;
        Xf[rr][n] = x2;
        a.xo[(size_t)(i0 + rr) * DM + n] = x2;
      }
    }
  }
  __syncthreads();

  // ---- LN1-next (or LNf) -> Abh/Abl ----
  ln16(Xf, Abh, Abl, a.lns, a.lnb, t);
  __syncthreads();

  #pragma unroll
  for (int kc = 0; kc < 8; ++kc) {
    af[kc]  = *(const bf16x8*)&Abh[lr][kc * 32 + lq * 8];
    afl[kc] = *(const bf16x8*)&Abl[lr][kc * 32 + lq * 8];
  }

  // ---- stage 6: qkv next / pair projection ----
  if (!LAST) {
    #pragma unroll 2
    for (int gi = 0; gi < 6; ++gi) {
      int g = w * 6 + gi;
      f32x4 ac = {0.f, 0.f, 0.f, 0.f};
      #pragma unroll
      for (int kc = 0; kc < 8; ++kc) {
        int off = ((kc * 48 + g) << 9) + (l << 3);
        ac = mfma3(af[kc], afl[kc], a.wnph + off, a.wnpl + off, ac);
      }
      int n = g * 16 + lr;
      float* dst = n < 256 ? a.qo : (n < 512 ? a.ko : a.vo);
      int nn = n & 255;
      #pragma unroll
      for (int r = 0; r < 4; ++r)
        dst[(size_t)(i0 + lq * 4 + r) * DM + nn] = ac[r];
    }
  } else {
    #pragma unroll 2
    for (int gi = 0; gi < 4; ++gi) {
      int g = w * 4 + gi;
      f32x4 ac = {0.f, 0.f, 0.f, 0.f};
      #pragma unroll
      for (int kc = 0; kc < 8; ++kc) {
        int off = ((kc * 32 + g) << 9) + (l << 3);
        ac = mfma3(af[kc], afl[kc], a.wnph + off, a.wnpl + off, ac);
      }
      int n = g * 16 + lr;
      float* dst = n < 256 ? a.qo : a.ko;
      const float* bias = n < 256 ? a.nb0 : a.nb1;
      int nn = n & 255;
      float bv = bias[nn];
      #pragma unroll
      for (int r = 0; r < 4; ++r)
        dst[(size_t)(i0 + lq * 4 + r) * DM + nn] = ac[r] + bv;
    }
  }
}

// ---------------------------------------------------------------------------
// Fused pair head (validated): LDS-staged q/k, W1p reg-prefetch, packed cvt.
#define PAIR_SMEM 74864

__global__ __launch_bounds__(256, 2) void k_pair(
    const float* __restrict__ pq, const float* __restrict__ pk,
    const unsigned short* __restrict__ W1p, const float* __restrict__ RB,
    const float* __restrict__ w2, const float* __restrict__ b2,
    float* __restrict__ out) {
  extern __shared__ char smem[];
  float* qs   = (float*)smem;
  float* ks   = (float*)(smem + 4160);
  float* RB_s = (float*)(smem + 37440);
  float* racc = (float*)(smem + 73840);

  int t = threadIdx.x;
  int j0 = blockIdx.x * 32;
  int i0 = blockIdx.y * 4;
  int w = t >> 6, l = t & 63;
  int q4 = l >> 4, l15 = l & 15;
  int mwv = w & 1, nwv = w >> 1;

  {
    int row = t >> 6, c4 = (t & 63) * 4;
    *(float4*)(qs + row * 260 + c4) = *(const float4*)(pq + (size_t)(i0 + row) * DM + c4);
    #pragma unroll
    for (int r8 = 0; r8 < 8; ++r8) {
      int idx = t + r8 * 256;
      int kr = idx >> 6, kc4 = (idx & 63) * 4;
      *(float4*)(ks + kr * 260 + kc4) = *(const float4*)(pk + (size_t)(j0 + kr) * DM + kc4);
    }
    int ddmin = i0 - j0 + 736;
    for (int idx = t; idx < 35 * 64; idx += 256) {
      int lc = idx >> 6, c4b = (idx & 63) * 4;
      *(float4*)(RB_s + lc * 260 + c4b) =
          *(const float4*)(RB + (size_t)(ddmin + lc) * 256 + c4b);
    }
    racc[t] = 0.f;
  }
  __syncthreads();

  const unsigned short* Bp = W1p + (size_t)(nwv * 8) * 512 + (size_t)l * 8;
  const float* q0p = qs + (mwv * 2) * 260;
  const float* q1p = qs + (mwv * 2 + 1) * 260;
  const float* k0p = ks + l15 * 260;
  const float* k1p = ks + (16 + l15) * 260;

  f32x4 acc[4][8];
  #pragma unroll
  for (int aa = 0; aa < 4; ++aa)
    #pragma unroll
    for (int bb = 0; bb < 8; ++bb) acc[aa][bb] = (f32x4){0.f, 0.f, 0.f, 0.f};

  bf16x8 bcur[8];
  #pragma unroll
  for (int nt = 0; nt < 8; ++nt) bcur[nt] = *(const bf16x8*)(Bp + nt * 512);

  for (int kc = 0; kc < 8; ++kc) {
    bf16x8 bnxt[8];
    if (kc < 7) {
      const unsigned short* bbn = Bp + (size_t)(kc + 1) * 8192;
      #pragma unroll
      for (int nt = 0; nt < 8; ++nt) bnxt[nt] = *(const bf16x8*)(bbn + nt * 512);
    }
    int c = kc * 32 + q4 * 8;
    float4 qa0 = *(const float4*)(q0p + c), qa1 = *(const float4*)(q0p + c + 4);
    float4 qb0 = *(const float4*)(q1p + c), qb1 = *(const float4*)(q1p + c + 4);
    float4 ka0 = *(const float4*)(k0p + c), ka1 = *(const float4*)(k0p + c + 4);
    float4 kb0 = *(const float4*)(k1p + c), kb1 = *(const float4*)(k1p + c + 4);

    union { bf16x8 v; unsigned u[4]; } af[4];
    af[0].u[0] = pk2(qa0.x*ka0.x, qa0.y*ka0.y); af[0].u[1] = pk2(qa0.z*ka0.z, qa0.w*ka0.w);
    af[0].u[2] = pk2(qa1.x*ka1.x, qa1.y*ka1.y); af[0].u[3] = pk2(qa1.z*ka1.z, qa1.w*ka1.w);
    af[1].u[0] = pk2(qa0.x*kb0.x, qa0.y*kb0.y); af[1].u[1] = pk2(qa0.z*kb0.z, qa0.w*kb0.w);
    af[1].u[2] = pk2(qa1.x*kb1.x, qa1.y*kb1.y); af[1].u[3] = pk2(qa1.z*kb1.z, qa1.w*kb1.w);
    af[2].u[0] = pk2(qb0.x*ka0.x, qb0.y*ka0.y); af[2].u[1] = pk2(qb0.z*ka0.z, qb0.w*ka0.w);
    af[2].u[2] = pk2(qb1.x*ka1.x, qb1.y*ka1.y); af[2].u[3] = pk2(qb1.z*ka1.z, qb1.w*ka1.w);
    af[3].u[0] = pk2(qb0.x*kb0.x, qb0.y*kb0.y); af[3].u[1] = pk2(qb0.z*kb0.z, qb0.w*kb0.w);
    af[3].u[2] = pk2(qb1.x*kb1.x, qb1.y*kb1.y); af[3].u[3] = pk2(qb1.z*kb1.z, qb1.w*kb1.w);

    #pragma unroll
    for (int mt = 0; mt < 4; ++mt)
      #pragma unroll
      for (int nt = 0; nt < 8; ++nt)
        acc[mt][nt] = __builtin_amdgcn_mfma_f32_16x16x32_bf16(af[mt].v, bcur[nt], acc[mt][nt], 0, 0, 0);
    if (kc < 7) {
      #pragma unroll
      for (int nt = 0; nt < 8; ++nt) bcur[nt] = bnxt[nt];
    }
  }

  float w20[8], w21[8];
  #pragma unroll
  for (int nt = 0; nt < 8; ++nt) {
    int n = nwv * 128 + nt * 16 + l15;
    w20[nt] = w2[n * 2];
    w21[nt] = w2[n * 2 + 1];
  }
  #pragma unroll
  for (int mt = 0; mt < 4; ++mt) {
    #pragma unroll
    for (int reg = 0; reg < 4; ++reg) {
      int r = mwv * 64 + mt * 16 + q4 * 4 + reg;
      int lc = (r >> 5) - (r & 31) + 31;
      float o0 = 0.f, o1 = 0.f;
      #pragma unroll
      for (int nt = 0; nt < 8; ++nt) {
        int n = nwv * 128 + nt * 16 + l15;
        float T = acc[mt][nt][reg] + RB_s[lc * 260 + n];
        T = fmaxf(T, 0.f);
        o0 = fmaf(T, w20[nt], o0);
        o1 = fmaf(T, w21[nt], o1);
      }
      #pragma unroll
      for (int s = 1; s < 16; s <<= 1) {
        o0 += __shfl_xor(o0, s);
        o1 += __shfl_xor(o1, s);
      }
      if (l15 == 0) {
        atomicAdd(&racc[r * 2 + 0], o0);
        atomicAdd(&racc[r * 2 + 1], o1);
      }
    }
  }
  __syncthreads();
  {
    int r = t >> 1, oo = t & 1;
    out[((size_t)(i0 + (r >> 5)) * LSEQ + (j0 + (r & 31))) * 2 + oo] = racc[t] + b2[oo];
  }
}

// ---------------------------------------------------------------------------
extern "C" void kernel_launch(void* const* d_in, const int* in_sizes, int n_in,
                              void* d_out, int out_size, void* d_ws, size_t ws_size,
                              hipStream_t stream) {
  const int*   seq      = (const int*)  d_in[0];
  const float* tok_emb  = (const float*)d_in[1];
  const float* rp_emb   = (const float*)d_in[2];
  const float* wq       = (const float*)d_in[3];
  const float* wk       = (const float*)d_in[4];
  const float* wv       = (const float*)d_in[5];
  const float* wo       = (const float*)d_in[6];
  const float* ln1_s    = (const float*)d_in[7];
  const float* ln1_b    = (const float*)d_in[8];
  const float* ln2_s    = (const float*)d_in[9];
  const float* ln2_b    = (const float*)d_in[10];
  const float* ffn_w1   = (const float*)d_in[11];
  const float* ffn_b1   = (const float*)d_in[12];
  const float* ffn_w2   = (const float*)d_in[13];
  const float* ffn_b2   = (const float*)d_in[14];
  const float* lnf_s    = (const float*)d_in[15];
  const float* lnf_b    = (const float*)d_in[16];
  const float* pair_q_w = (const float*)d_in[17];
  const float* pair_q_b = (const float*)d_in[18];
  const float* pair_k_w = (const float*)d_in[19];
  const float* pair_k_b = (const float*)d_in[20];
  const float* pair_rp  = (const float*)d_in[21];
  const float* cls_w1   = (const float*)d_in[22];
  const float* cls_b1   = (const float*)d_in[23];
  const float* cls_w2   = (const float*)d_in[24];
  const float* cls_b2   = (const float*)d_in[25];
  float* out = (float*)d_out;

  char* ws = (char*)d_ws;
  float* xb0 = (float*)(ws + 0);
  float* xb1 = (float*)(ws + 786432);
  float* qb[2] = { (float*)(ws + 1572864), (float*)(ws + 3932160) };
  float* kb[2] = { (float*)(ws + 2359296), (float*)(ws + 4718592) };
  float* vb[2] = { (float*)(ws + 3145728), (float*)(ws + 5505024) };
  float* o   = (float*)(ws + 6291456);
  float* pq  = (float*)(ws + 7077888);
  float* pk  = (float*)(ws + 7864320);
  float* RB  = (float*)(ws + 8650752);
  unsigned short* W1p = (unsigned short*)(ws + 10223616);
  float* abias = (float*)(ws + 10354688);
  // packed bf16 MFMA weights, hi + residual-lo
  unsigned short* Woph   = (unsigned short*)(ws + 10403840);  // 8 x 65536  x2B
  unsigned short* Wopl   = (unsigned short*)(ws + 11452416);
  unsigned short* W1ph   = (unsigned short*)(ws + 12500992);  // 8 x 262144 x2B
  unsigned short* W1pl   = (unsigned short*)(ws + 16695296);
  unsigned short* W2ph   = (unsigned short*)(ws + 20889600);  // 8 x 262144 x2B
  unsigned short* W2pl   = (unsigned short*)(ws + 25083904);
  unsigned short* Wqkvh  = (unsigned short*)(ws + 29278208);  // 8 x 196608 x2B
  unsigned short* Wqkvl  = (unsigned short*)(ws + 32423936);
  unsigned short* Wpairh = (unsigned short*)(ws + 35569664);  // 131072 x2B
  unsigned short* Wpairl = (unsigned short*)(ws + 35831808);

  (void)in_sizes; (void)n_in; (void)out_size; (void)ws_size;

  hipFuncSetAttribute(reinterpret_cast<const void*>(k_pair),
                      hipFuncAttributeMaxDynamicSharedMemorySize, PAIR_SMEM);
  hipFuncSetAttribute(reinterpret_cast<const void*>(k_attn2),
                      hipFuncAttributeMaxDynamicSharedMemorySize, ATTN_SMEM);
  hipFuncSetAttribute(reinterpret_cast<const void*>(k_tail2<0>),
                      hipFuncAttributeMaxDynamicSharedMemorySize, TAIL_SMEM);
  hipFuncSetAttribute(reinterpret_cast<const void*>(k_tail2<1>),
                      hipFuncAttributeMaxDynamicSharedMemorySize, TAIL_SMEM);

  k_prep<<<3638, 256, 0, stream>>>(seq, tok_emb, rp_emb, wq, wk, wv, wo,
                                   ffn_w1, ffn_w2, ln1_s, ln1_b,
                                   pair_rp, cls_w1, cls_b1, pair_q_w, pair_k_w,
                                   xb0, qb[0], kb[0], vb[0], RB, W1p, abias,
                                   Woph, Wopl, W1ph, W1pl, W2ph, W2pl,
                                   Wqkvh, Wqkvl, Wpairh, Wpairl);

  for (int l = 0; l < NLAYER; ++l) {
    int pi = l & 1, po = pi ^ 1;
    float* xin  = (l & 1) ? xb1 : xb0;
    float* xout = (l & 1) ? xb0 : xb1;

    k_attn2<<<dim3(48, 8), 256, ATTN_SMEM, stream>>>(qb[pi], kb[pi], vb[pi], abias, o);

    TB a{};
    a.o = o; a.xin = xin; a.xo = xout;
    a.woph = Woph + ((size_t)l << 16); a.wopl = Wopl + ((size_t)l << 16);
    a.ln2s = ln2_s + l * DM; a.ln2b = ln2_b + l * DM;
    a.w1ph = W1ph + ((size_t)l << 18); a.w1pl = W1pl + ((size_t)l << 18);
    a.fb1 = ffn_b1 + (size_t)l * DFF;
    a.w2ph = W2ph + ((size_t)l << 18); a.w2pl = W2pl + ((size_t)l << 18);
    a.fb2 = ffn_b2 + (size_t)l * DM;
    if (l < NLAYER - 1) {
      a.wnph = Wqkvh + (size_t)(l + 1) * 196608;
      a.wnpl = Wqkvl + (size_t)(l + 1) * 196608;
      a.lns = ln1_s + (l + 1) * DM; a.lnb = ln1_b + (l + 1) * DM;
      a.qo = qb[po]; a.ko = kb[po]; a.vo = vb[po];
      k_tail2<0><<<48, 512, TAIL_SMEM, stream>>>(a);
    } else {
      a.wnph = Wpairh; a.wnpl = Wpairl;
      a.nb0 = pair_q_b; a.nb1 = pair_k_b;
      a.lns = lnf_s; a.lnb = lnf_b;
      a.qo = pq; a.ko = pk;
      k_tail2<1><<<48, 512, TAIL_SMEM, stream>>>(a);
    }
  }

  k_pair<<<dim3(24, 192), 256, PAIR_SMEM, stream>>>(pq, pk, W1p, RB, cls_w2, cls_b2, out);
}

// Round 3
// 658.148 us; speedup vs baseline: 2.0689x; 1.5378x over previous
//
#include <hip/hip_runtime.h>
#include <hip/hip_bf16.h>
#include <stdint.h>

// ---------------------------------------------------------------------------
#define LSEQ 768
#define DM   256
#define NH   8
#define DK   32
#define DFF  1024
#define NLAYER 8
#define NDD  1535
// ---------------------------------------------------------------------------

typedef __attribute__((ext_vector_type(8))) short     bf16x8;
typedef __attribute__((ext_vector_type(8))) _Float16  f16x8;
typedef __attribute__((ext_vector_type(4))) float     f32x4;

__device__ __forceinline__ unsigned short f2bf(float f) {
  unsigned u = __float_as_uint(f);
  u += 0x7fffu + ((u >> 16) & 1u);       // RNE
  return (unsigned short)(u >> 16);
}
__device__ __forceinline__ unsigned short f2h(float f) {
  union { _Float16 h; unsigned short s; } c;
  c.h = (_Float16)f;                     // v_cvt_f16_f32 (RNE)
  return c.s;
}
__device__ __forceinline__ unsigned pk2(float a, float b) {
  __hip_bfloat162 h = __float22bfloat162_rn(make_float2(a, b));
  union { __hip_bfloat162 h; unsigned u; } c; c.h = h;
  return c.u;
}
__device__ __forceinline__ int bucket_of(int dd) {
  int rel = dd - 767;
  int ret = rel < 0 ? 32 : 0;
  int arp = rel < 0 ? -rel : rel;
  if (arp < 16) return ret + arp;
  const float lr = 2.772588722239781f;   // float(np.log(16))
  float val = logf((float)arp * 0.0625f) / lr * 16.0f;
  int vi = 16 + (int)val;
  return ret + (vi < 31 ? vi : 31);
}

// ---------------------------------------------------------------------------
// MFMA B-fragment packers: row-major [K][N] fp32 -> [K/32][N/16][lane][8] fp16
// (lane layout: n = g*16 + (lane&15), k = kc*32 + (lane>>4)*8 + e)
__device__ __forceinline__ void pack8h(unsigned short* dst, int id,
                                       const float* src, int N, int G) {
  int lane = (id >> 3) & 63;
  int rem = id >> 9;
  int g = rem % G, kc = rem / G;
  int kb = kc * 32 + ((lane >> 4) << 3);
  int n = g * 16 + (lane & 15);
  union { unsigned short s[8]; uint4 v; } U;
  #pragma unroll
  for (int e = 0; e < 8; ++e) U.s[e] = f2h(src[(size_t)(kb + e) * N + n]);
  *(uint4*)(dst + id) = U.v;
}

// N-concat of up to 3 [K][256] matrices (qkv: G=48, pair q/k: G=32)
__device__ __forceinline__ void pack8h_cat(unsigned short* dst, int id,
                                           const float* s0, const float* s1,
                                           const float* s2, int G) {
  int lane = (id >> 3) & 63;
  int rem = id >> 9;
  int g = rem % G, kc = rem / G;
  int kb = kc * 32 + ((lane >> 4) << 3);
  int n = g * 16 + (lane & 15);
  const float* sp = n < 256 ? s0 : (n < 512 ? s1 : s2);
  int nn = n & 255;
  union { unsigned short s[8]; uint4 v; } U;
  #pragma unroll
  for (int e = 0; e < 8; ++e) U.s[e] = f2h(sp[(size_t)(kb + e) * 256 + nn]);
  *(uint4*)(dst + id) = U.v;
}

// ---------------------------------------------------------------------------
// Legacy 64x64 GEMM tile (k_prep only; plain caching, gather variants).
// LDS from smc: As 2x32x68 @0, Bs @17408, stat @34816, red @35328 -> 37376.
template <int LN, int GR>
__device__ void gemm_tile(const float* gsrc, const int* seqIdx,
                          const float* B, const float* bias, float* C,
                          const float* lns, const float* lnb,
                          int M, int K, int N, int m0, int n0, char* smc) {
  float (*As)[32][68] = (float (*)[32][68])smc;
  float (*Bs)[32][68] = (float (*)[32][68])(smc + 17408);
  float (*stat)[2]    = (float (*)[2])(smc + 34816);
  float (*red)[8]     = (float (*)[8])(smc + 35328);

  int t = threadIdx.x;
  int arow = t >> 2, akq = (t & 3) * 8;
  int mg = m0 + arow;
  int mgc = mg < M ? mg : M - 1;
  const float* Ar = (GR == 1) ? (gsrc + (size_t)seqIdx[mgc] * K)
                              : (gsrc + (size_t)bucket_of(mgc) * K);
  float mean = 0.f, rstd = 0.f;
  if (LN) {
    int lq = t & 3;
    float s = 0.f, s2 = 0.f;
    const float* p = Ar + lq * 64;
    #pragma unroll
    for (int c = 0; c < 64; c += 4) {
      float4 v = *(const float4*)(p + c);
      s  += v.x + v.y + v.z + v.w;
      s2 += v.x * v.x + v.y * v.y + v.z * v.z + v.w * v.w;
    }
    red[arow][lq] = s; red[arow][lq + 4] = s2;
    __syncthreads();
    if (lq == 0) {
      float sm = red[arow][0] + red[arow][1] + red[arow][2] + red[arow][3];
      float sq = red[arow][4] + red[arow][5] + red[arow][6] + red[arow][7];
      float m = sm * (1.f / 256.f);
      float v = sq * (1.f / 256.f) - m * m;
      stat[arow][0] = m;
      stat[arow][1] = rsqrtf(v + 1e-5f);
    }
    __syncthreads();
    mean = stat[arow][0]; rstd = stat[arow][1];
  }

  int bkr = t >> 3, bn8 = (t & 7) * 8;
  int ty = t >> 4, tx = t & 15;
  float acc[4][4] = {};
  int nk = K >> 5;

  for (int kt = 0; kt < nk; ++kt) {
    int k0 = kt << 5;
    float4 a0 = *(const float4*)(Ar + k0 + akq);
    float4 a1 = *(const float4*)(Ar + k0 + akq + 4);
    if (LN) {
      float4 ls0 = *(const float4*)(lns + k0 + akq), ls1 = *(const float4*)(lns + k0 + akq + 4);
      float4 lb0 = *(const float4*)(lnb + k0 + akq), lb1 = *(const float4*)(lnb + k0 + akq + 4);
      a0.x=(a0.x-mean)*rstd*ls0.x+lb0.x; a0.y=(a0.y-mean)*rstd*ls0.y+lb0.y;
      a0.z=(a0.z-mean)*rstd*ls0.z+lb0.z; a0.w=(a0.w-mean)*rstd*ls0.w+lb0.w;
      a1.x=(a1.x-mean)*rstd*ls1.x+lb1.x; a1.y=(a1.y-mean)*rstd*ls1.y+lb1.y;
      a1.z=(a1.z-mean)*rstd*ls1.z+lb1.z; a1.w=(a1.w-mean)*rstd*ls1.w+lb1.w;
    }
    int cur = kt & 1;
    As[cur][akq+0][arow]=a0.x; As[cur][akq+1][arow]=a0.y; As[cur][akq+2][arow]=a0.z; As[cur][akq+3][arow]=a0.w;
    As[cur][akq+4][arow]=a1.x; As[cur][akq+5][arow]=a1.y; As[cur][akq+6][arow]=a1.z; As[cur][akq+7][arow]=a1.w;
    *(float4*)&Bs[cur][bkr][bn8] = *(const float4*)(B + (size_t)(k0 + bkr) * N + n0 + bn8);
    *(float4*)&Bs[cur][bkr][bn8+4] = *(const float4*)(B + (size_t)(k0 + bkr) * N + n0 + bn8 + 4);
    __syncthreads();
    #pragma unroll 8
    for (int kk = 0; kk < 32; ++kk) {
      float4 a = *(float4*)&As[cur][kk][ty * 4];
      float4 b = *(float4*)&Bs[cur][kk][tx * 4];
      acc[0][0]=fmaf(a.x,b.x,acc[0][0]); acc[0][1]=fmaf(a.x,b.y,acc[0][1]);
      acc[0][2]=fmaf(a.x,b.z,acc[0][2]); acc[0][3]=fmaf(a.x,b.w,acc[0][3]);
      acc[1][0]=fmaf(a.y,b.x,acc[1][0]); acc[1][1]=fmaf(a.y,b.y,acc[1][1]);
      acc[1][2]=fmaf(a.y,b.z,acc[1][2]); acc[1][3]=fmaf(a.y,b.w,acc[1][3]);
      acc[2][0]=fmaf(a.z,b.x,acc[2][0]); acc[2][1]=fmaf(a.z,b.y,acc[2][1]);
      acc[2][2]=fmaf(a.z,b.z,acc[2][2]); acc[2][3]=fmaf(a.z,b.w,acc[2][3]);
      acc[3][0]=fmaf(a.w,b.x,acc[3][0]); acc[3][1]=fmaf(a.w,b.y,acc[3][1]);
      acc[3][2]=fmaf(a.w,b.z,acc[3][2]); acc[3][3]=fmaf(a.w,b.w,acc[3][3]);
    }
    __syncthreads();
  }

  #pragma unroll
  for (int u = 0; u < 4; ++u) {
    int m = m0 + ty * 4 + u;
    if (m < M) {
      int n = n0 + tx * 4;
      float4 val = make_float4(acc[u][0], acc[u][1], acc[u][2], acc[u][3]);
      if (bias) {
        float4 bv = *(const float4*)(bias + n);
        val.x += bv.x; val.y += bv.y; val.z += bv.z; val.w += bv.w;
      }
      *(float4*)(C + (size_t)m * N + n) = val;
    }
  }
}

// ---------------------------------------------------------------------------
// Prep: RB gemm + qkv layer0 + embed + abias + W1p pack + fp16 weight packs.
__global__ __launch_bounds__(256, 2) void k_prep(
    const int* __restrict__ seq, const float* __restrict__ tok_emb,
    const float* __restrict__ rp_emb,
    const float* __restrict__ wq, const float* __restrict__ wk,
    const float* __restrict__ wv, const float* __restrict__ wo,
    const float* __restrict__ ffn_w1, const float* __restrict__ ffn_w2,
    const float* __restrict__ ln1s0, const float* __restrict__ ln1b0,
    const float* __restrict__ pair_rp, const float* __restrict__ cls_w1,
    const float* __restrict__ cls_b1,
    const float* __restrict__ pair_q_w, const float* __restrict__ pair_k_w,
    float* x0, float* q0, float* k0, float* v0, float* RB,
    unsigned short* W1p, float* abias,
    unsigned short* Wop, unsigned short* W1pk, unsigned short* W2pk,
    unsigned short* Wqkvp, unsigned short* Wpairp) {
  __shared__ __align__(16) char sm[37376];
  int b = blockIdx.x, t = threadIdx.x;
  if (b < 96) {
    int m0 = (b % 24) * 64, n0 = (b / 24) * 64;
    gemm_tile<0,2>(pair_rp, nullptr, cls_w1, cls_b1, RB,
                   nullptr, nullptr, NDD, 256, 256, m0, n0, sm);
  } else if (b < 240) {
    int u = b - 96;
    int n0g = (u % 12) * 64, m0 = (u / 12) * 64;
    int bi = n0g >> 8, n0 = n0g & 255;
    const float* B = bi == 0 ? wq : (bi == 1 ? wk : wv);
    float* C = bi == 0 ? q0 : (bi == 1 ? k0 : v0);
    gemm_tile<1,1>(tok_emb, seq, B, nullptr, C,
                   ln1s0, ln1b0, LSEQ, 256, 256, m0, n0, sm);
  } else if (b < 432) {
    int row = (b - 240) * 4 + (t >> 6), c = (t & 63) * 4;
    *(float4*)(x0 + (size_t)row * DM + c) =
        *(const float4*)(tok_emb + (size_t)seq[row] * DM + c);
  } else if (b < 438) {
    int dd = (b - 432) * 256 + t;
    if (dd < NDD) {
      int bk = bucket_of(dd);
      #pragma unroll
      for (int h = 0; h < NH; ++h) abias[dd * 8 + h] = rp_emb[bk * 8 + h];
    }
  } else if (b < 502) {
    int base = (b - 438) * 1024 + t * 4;
    #pragma unroll
    for (int uu = 0; uu < 4; ++uu) {
      int id = base + uu;
      int e = id & 7, lane = (id >> 3) & 63, g = (id >> 9) & 15, kc = id >> 13;
      int kg = kc * 32 + (lane >> 4) * 8 + e;
      int n  = g * 16 + (lane & 15);
      W1p[id] = f2bf(cls_w1[(size_t)kg * 256 + n]);
    }
  } else {
    // fp16 MFMA weight packing: 3136 blocks x 2048 elems
    int u = (b - 502) * 2048 + t * 8;
    if (u < 524288) {                       // wo: 8 x [256][256], G=16
      int layer = u >> 16, id = u & 65535;
      pack8h(Wop + ((size_t)layer << 16), id, wo + ((size_t)layer << 16), 256, 16);
    } else if (u < 2621440) {               // ffn_w1: 8 x [256][1024], G=64
      int v2 = u - 524288; int layer = v2 >> 18, id = v2 & 262143;
      pack8h(W1pk + ((size_t)layer << 18), id, ffn_w1 + ((size_t)layer << 18), 1024, 64);
    } else if (u < 4718592) {               // ffn_w2: 8 x [1024][256], G=16
      int v2 = u - 2621440; int layer = v2 >> 18, id = v2 & 262143;
      pack8h(W2pk + ((size_t)layer << 18), id, ffn_w2 + ((size_t)layer << 18), 256, 16);
    } else if (u < 6291456) {               // qkv concat: 8 x [256][768], G=48
      int v2 = u - 4718592; int layer = v2 / 196608, id = v2 - layer * 196608;
      pack8h_cat(Wqkvp + (size_t)layer * 196608, id,
                 wq + ((size_t)layer << 16), wk + ((size_t)layer << 16),
                 wv + ((size_t)layer << 16), 48);
    } else {                                // pair q/k concat: [256][512], G=32
      int id = u - 6291456;
      pack8h_cat(Wpairp, id, pair_q_w, pair_k_w, pair_k_w, 32);
    }
  }
}

// ---------------------------------------------------------------------------
// Attention (validated round 7): 16 q-rows x 1 head per block.
#define ATTN_SMEM 72960

__global__ __launch_bounds__(256, 2) void k_attn2(
    const float* __restrict__ q, const float* __restrict__ k,
    const float* __restrict__ v, const float* __restrict__ abias,
    float* __restrict__ o) {
  extern __shared__ char sm[];
  float* S  = (float*)sm;
  float* KV = (float*)(sm + 49664);
  float* QS = (float*)(sm + 66560);
  float* BS = (float*)(sm + 68672);
  float (*red)[16] = (float (*)[16])(sm + 71808);
  float* mrow = (float*)(sm + 72832);
  float* linv = (float*)(sm + 72896);

  int i0 = blockIdx.x * 16, h = blockIdx.y, hc = h * DK;
  int t = threadIdx.x;

  for (int u = t; u < 783; u += 256)
    BS[u] = abias[(size_t)(i0 + u) * 8 + h];
  {
    int r = t >> 4, c = t & 15;
    const float inv = 0.17677669529663687f;   // 1/sqrt(32)
    QS[r * 33 + c]      = q[(size_t)(i0 + r) * DM + hc + c] * inv;
    QS[r * 33 + c + 16] = q[(size_t)(i0 + r) * DM + hc + c + 16] * inv;
  }

  int kx = t & 31, ry = t >> 5;
  int key = t >> 1, half = t & 1;

  for (int cc = 0; cc < 6; ++cc) {
    const float* kp = k + (size_t)(cc * 128 + key) * DM + hc + half * 16;
    float4 L0 = *(const float4*)(kp);
    float4 L1 = *(const float4*)(kp + 4);
    float4 L2 = *(const float4*)(kp + 8);
    float4 L3 = *(const float4*)(kp + 12);
    __syncthreads();
    int cb = half * 16;
    KV[(cb+ 0)*132+key]=L0.x; KV[(cb+ 1)*132+key]=L0.y; KV[(cb+ 2)*132+key]=L0.z; KV[(cb+ 3)*132+key]=L0.w;
    KV[(cb+ 4)*132+key]=L1.x; KV[(cb+ 5)*132+key]=L1.y; KV[(cb+ 6)*132+key]=L1.z; KV[(cb+ 7)*132+key]=L1.w;
    KV[(cb+ 8)*132+key]=L2.x; KV[(cb+ 9)*132+key]=L2.y; KV[(cb+10)*132+key]=L2.z; KV[(cb+11)*132+key]=L2.w;
    KV[(cb+12)*132+key]=L3.x; KV[(cb+13)*132+key]=L3.y; KV[(cb+14)*132+key]=L3.z; KV[(cb+15)*132+key]=L3.w;
    __syncthreads();

    float s0x=0,s0y=0,s0z=0,s0w=0, s1x=0,s1y=0,s1z=0,s1w=0;
    #pragma unroll
    for (int kk = 0; kk < 32; ++kk) {
      float q0 = QS[(ry*2    )*33 + kk];
      float q1 = QS[(ry*2 + 1)*33 + kk];
      float4 kv4 = *(const float4*)&KV[kk*132 + kx*4];
      s0x = fmaf(q0, kv4.x, s0x); s0y = fmaf(q0, kv4.y, s0y);
      s0z = fmaf(q0, kv4.z, s0z); s0w = fmaf(q0, kv4.w, s0w);
      s1x = fmaf(q1, kv4.x, s1x); s1y = fmaf(q1, kv4.y, s1y);
      s1z = fmaf(q1, kv4.z, s1z); s1w = fmaf(q1, kv4.w, s1w);
    }
    int jb = cc * 128 + kx * 4;
    int r0 = ry * 2, r1 = r0 + 1;
    S[r0*776 + jb+0] = s0x + BS[r0 + 767 - (jb+0)];
    S[r0*776 + jb+1] = s0y + BS[r0 + 767 - (jb+1)];
    S[r0*776 + jb+2] = s0z + BS[r0 + 767 - (jb+2)];
    S[r0*776 + jb+3] = s0w + BS[r0 + 767 - (jb+3)];
    S[r1*776 + jb+0] = s1x + BS[r1 + 767 - (jb+0)];
    S[r1*776 + jb+1] = s1y + BS[r1 + 767 - (jb+1)];
    S[r1*776 + jb+2] = s1z + BS[r1 + 767 - (jb+2)];
    S[r1*776 + jb+3] = s1w + BS[r1 + 767 - (jb+3)];
  }
  __syncthreads();

  {
    int ti = t >> 4, tj = t & 15;
    float mx = -1e30f;
    for (int jc = 0; jc < 48; ++jc)
      mx = fmaxf(mx, S[ti*776 + jc*16 + tj]);
    red[ti][tj] = mx;
    __syncthreads();
    if (tj == 0) {
      float m2 = red[ti][0];
      #pragma unroll
      for (int u = 1; u < 16; ++u) m2 = fmaxf(m2, red[ti][u]);
      mrow[ti] = m2;
    }
    __syncthreads();
    float m2 = mrow[ti];
    float sum = 0.f;
    for (int jc = 0; jc < 48; ++jc) {
      int j = jc*16 + tj;
      float e = __expf(S[ti*776 + j] - m2);
      S[ti*776 + j] = e;
      sum += e;
    }
    red[ti][tj] = sum;
    __syncthreads();
    if (tj == 0) {
      float s2 = 0.f;
      #pragma unroll
      for (int u = 0; u < 16; ++u) s2 += red[ti][u];
      linv[ti] = 1.f / s2;
    }
  }

  int cp = t & 15, jg = t >> 4;
  int c0 = cp * 2, c1 = c0 + 1;
  float oc0[16] = {}, oc1[16] = {};
  for (int cc = 0; cc < 6; ++cc) {
    const float* vp = v + (size_t)(cc * 128 + key) * DM + hc + half * 16;
    float4 L0 = *(const float4*)(vp);
    float4 L1 = *(const float4*)(vp + 4);
    float4 L2 = *(const float4*)(vp + 8);
    float4 L3 = *(const float4*)(vp + 12);
    __syncthreads();
    int cb = half * 16;
    KV[(cb+ 0)*132+key]=L0.x; KV[(cb+ 1)*132+key]=L0.y; KV[(cb+ 2)*132+key]=L0.z; KV[(cb+ 3)*132+key]=L0.w;
    KV[(cb+ 4)*132+key]=L1.x; KV[(cb+ 5)*132+key]=L1.y; KV[(cb+ 6)*132+key]=L1.z; KV[(cb+ 7)*132+key]=L1.w;
    KV[(cb+ 8)*132+key]=L2.x; KV[(cb+ 9)*132+key]=L2.y; KV[(cb+10)*132+key]=L2.z; KV[(cb+11)*132+key]=L2.w;
    KV[(cb+12)*132+key]=L3.x; KV[(cb+13)*132+key]=L3.y; KV[(cb+14)*132+key]=L3.z; KV[(cb+15)*132+key]=L3.w;
    __syncthreads();

    #pragma unroll
    for (int jj2 = 0; jj2 < 2; ++jj2) {
      int jb = jg * 8 + jj2 * 4;
      float4 vA = *(const float4*)&KV[c0*132 + jb];
      float4 vB = *(const float4*)&KV[c1*132 + jb];
      #pragma unroll
      for (int r = 0; r < 16; ++r) {
        float4 sv = *(const float4*)&S[r*776 + cc*128 + jb];
        oc0[r] += sv.x*vA.x + sv.y*vA.y + sv.z*vA.z + sv.w*vA.w;
        oc1[r] += sv.x*vB.x + sv.y*vB.y + sv.z*vB.z + sv.w*vB.w;
      }
    }
  }

  #pragma unroll
  for (int h2 = 0; h2 < 2; ++h2) {
    __syncthreads();
    #pragma unroll
    for (int r = 0; r < 8; ++r) {
      KV[(jg*8 + r)*32 + c0] = oc0[h2*8 + r];
      KV[(jg*8 + r)*32 + c1] = oc1[h2*8 + r];
    }
    __syncthreads();
    int r = t >> 5, c = t & 31;
    float s = 0.f;
    #pragma unroll
    for (int jgg = 0; jgg < 16; ++jgg) s += KV[(jgg*8 + r)*32 + c];
    o[(size_t)(i0 + h2*8 + r) * DM + hc + c] = s * linv[h2*8 + r];
  }
}

// ---------------------------------------------------------------------------
// fp16-MFMA fused layer tail v3: 96 blocks x 512 threads, 8 rows/block.
// Weights pre-packed fp16; every weight stream register-double-buffered.
// MFMA C-tile rows 8..15 are deliberate don't-cares (A rows 8..15 zero/junk);
// only lq<2 lanes (C rows 0..7) store.
struct TC {
  const float* o; const float* xin;
  const unsigned short* wop;
  const float* ln2s; const float* ln2b;
  const unsigned short* w1p; const float* fb1;
  const unsigned short* w2p; const float* fb2;
  const unsigned short* wnp;
  const float* lns; const float* lnb;
  const float* nb0; const float* nb1;
  float *qo, *ko, *vo, *xo;
};

// LN over 8 rows x 256 cols: one wave per row, full-wave shuffle reduce.
__device__ __forceinline__ void ln8(float (*Xf)[260], _Float16 (*Ab)[264],
                                    const float* s, const float* b, int t) {
  int r = t >> 6, j = t & 63;
  int c0 = j * 4;
  float4 x = *(const float4*)&Xf[r][c0];
  float s1 = x.x + x.y + x.z + x.w;
  float s2 = x.x*x.x + x.y*x.y + x.z*x.z + x.w*x.w;
  #pragma unroll
  for (int m = 1; m < 64; m <<= 1) {
    s1 += __shfl_xor(s1, m);
    s2 += __shfl_xor(s2, m);
  }
  float mean = s1 * (1.f / 256.f);
  float var  = s2 * (1.f / 256.f) - mean * mean;
  float rs = rsqrtf(var + 1e-5f);
  union { _Float16 h[4]; uint2 u; } cv;
  cv.h[0] = (_Float16)((x.x - mean) * rs * s[c0+0] + b[c0+0]);
  cv.h[1] = (_Float16)((x.y - mean) * rs * s[c0+1] + b[c0+1]);
  cv.h[2] = (_Float16)((x.z - mean) * rs * s[c0+2] + b[c0+2]);
  cv.h[3] = (_Float16)((x.w - mean) * rs * s[c0+3] + b[c0+3]);
  *(uint2*)&Ab[r][c0] = cv.u;
}

template <int LAST>
__global__ __launch_bounds__(512) void k_tail3(TC a) {
  __shared__ float    Xf[8][260];     // residual stream (fp32)
  __shared__ _Float16 Ab[16][264];    // fp16 A-frag buffer (rows 8..15 = 0)
  __shared__ _Float16 Fb[16][1032];   // fp16 ffn1 output (rows 8..15 junk)

  int t = threadIdx.x;
  int i0 = blockIdx.x * 8;
  int w = t >> 6, l = t & 63;
  int lr = l & 15, lq = l >> 4;

  // ---- stage 0: O -> Ab (fp16), xin -> Xf; zero Ab rows 8..15 ----
  {
    int row = t >> 6, col = (t & 63) * 4;
    float4 v0 = *(const float4*)(a.o + (size_t)(i0 + row) * DM + col);
    union { _Float16 h[4]; uint2 u; } cv;
    cv.h[0] = (_Float16)v0.x; cv.h[1] = (_Float16)v0.y;
    cv.h[2] = (_Float16)v0.z; cv.h[3] = (_Float16)v0.w;
    *(uint2*)&Ab[row][col] = cv.u;
    *(float4*)&Xf[row][col] = *(const float4*)(a.xin + (size_t)(i0 + row) * DM + col);
    for (int z = t; z < 1056; z += 512) ((unsigned*)&Ab[8][0])[z] = 0;
  }
  __syncthreads();

  f16x8 af[8];
  #pragma unroll
  for (int kc = 0; kc < 8; ++kc)
    af[kc] = *(const f16x8*)&Ab[lr][kc * 32 + lq * 8];

  // ---- stage 1: X1 = xin + O@Wo (wave w owns cols [w*32, w*32+31]) ----
  {
    const unsigned short* wp = a.wop + (size_t)l * 8;
    int g0 = w * 2, g1 = g0 + 1;
    f16x8 wb0[8], wb1[8];
    #pragma unroll
    for (int kc = 0; kc < 8; ++kc) {
      wb0[kc] = *(const f16x8*)(wp + ((kc * 16 + g0) << 9));
      wb1[kc] = *(const f16x8*)(wp + ((kc * 16 + g1) << 9));
    }
    f32x4 a0v = {0.f,0.f,0.f,0.f}, a1v = {0.f,0.f,0.f,0.f};
    #pragma unroll
    for (int kc = 0; kc < 8; ++kc) {
      a0v = __builtin_amdgcn_mfma_f32_16x16x32_f16(af[kc], wb0[kc], a0v, 0, 0, 0);
      a1v = __builtin_amdgcn_mfma_f32_16x16x32_f16(af[kc], wb1[kc], a1v, 0, 0, 0);
    }
    if (lq < 2) {
      #pragma unroll
      for (int r = 0; r < 4; ++r) {
        Xf[lq * 4 + r][g0 * 16 + lr] += a0v[r];
        Xf[lq * 4 + r][g1 * 16 + lr] += a1v[r];
      }
    }
  }
  __syncthreads();

  // ---- LN2 -> Ab ----
  ln8(Xf, Ab, a.ln2s, a.ln2b, t);
  __syncthreads();

  #pragma unroll
  for (int kc = 0; kc < 8; ++kc)
    af[kc] = *(const f16x8*)&Ab[lr][kc * 32 + lq * 8];

  // ---- stage 3: ffn1 + gelu -> Fb (wave w owns cols [w*128, w*128+127]) ----
  {
    const unsigned short* wp = a.w1p + (size_t)l * 8;
    f16x8 cur[8], nxt[8];
    #pragma unroll
    for (int kc = 0; kc < 8; ++kc)
      cur[kc] = *(const f16x8*)(wp + ((kc * 64 + w * 8) << 9));
    #pragma unroll
    for (int gi = 0; gi < 8; ++gi) {
      int g = w * 8 + gi;
      if (gi < 7) {
        #pragma unroll
        for (int kc = 0; kc < 8; ++kc)
          nxt[kc] = *(const f16x8*)(wp + ((kc * 64 + g + 1) << 9));
      }
      f32x4 ac = {0.f,0.f,0.f,0.f};
      #pragma unroll
      for (int kc = 0; kc < 8; ++kc)
        ac = __builtin_amdgcn_mfma_f32_16x16x32_f16(af[kc], cur[kc], ac, 0, 0, 0);
      int n = g * 16 + lr;
      float bb1 = a.fb1[n];
      #pragma unroll
      for (int r = 0; r < 4; ++r) {
        float v = ac[r] + bb1;
        v = 0.5f * v * (1.f + erff(v * 0.70710678118654752f));
        Fb[lq * 4 + r][n] = (_Float16)v;   // rows 8..15 = junk, never stored
      }
      if (gi < 7) {
        #pragma unroll
        for (int kc = 0; kc < 8; ++kc) cur[kc] = nxt[kc];
      }
    }
  }
  __syncthreads();

  // ---- stage 4: X2 = X1 + F@W2 + b2, store xo ----
  {
    const unsigned short* wp = a.w2p + (size_t)l * 8;
    int g0 = w * 2, g1 = g0 + 1;
    f32x4 ac0 = {0.f,0.f,0.f,0.f}, ac1 = {0.f,0.f,0.f,0.f};
    f16x8 c0[8], c1[8], n0[8], n1[8];
    #pragma unroll
    for (int k8 = 0; k8 < 8; ++k8) {
      c0[k8] = *(const f16x8*)(wp + ((k8 * 16 + g0) << 9));
      c1[k8] = *(const f16x8*)(wp + ((k8 * 16 + g1) << 9));
    }
    #pragma unroll
    for (int bb = 0; bb < 4; ++bb) {
      if (bb < 3) {
        #pragma unroll
        for (int k8 = 0; k8 < 8; ++k8) {
          int kc = (bb + 1) * 8 + k8;
          n0[k8] = *(const f16x8*)(wp + ((kc * 16 + g0) << 9));
          n1[k8] = *(const f16x8*)(wp + ((kc * 16 + g1) << 9));
        }
      }
      #pragma unroll
      for (int k8 = 0; k8 < 8; ++k8) {
        int kc = bb * 8 + k8;
        f16x8 fa = *(const f16x8*)&Fb[lr][kc * 32 + lq * 8];
        ac0 = __builtin_amdgcn_mfma_f32_16x16x32_f16(fa, c0[k8], ac0, 0, 0, 0);
        ac1 = __builtin_amdgcn_mfma_f32_16x16x32_f16(fa, c1[k8], ac1, 0, 0, 0);
      }
      if (bb < 3) {
        #pragma unroll
        for (int k8 = 0; k8 < 8; ++k8) { c0[k8] = n0[k8]; c1[k8] = n1[k8]; }
      }
    }
    if (lq < 2) {
      int na = g0 * 16 + lr, nb = g1 * 16 + lr;
      float ba = a.fb2[na], bbv = a.fb2[nb];
      #pragma unroll
      for (int r = 0; r < 4; ++r) {
        int rr = lq * 4 + r;
        float xa = Xf[rr][na] + ac0[r] + ba;
        float xb = Xf[rr][nb] + ac1[r] + bbv;
        Xf[rr][na] = xa; Xf[rr][nb] = xb;
        a.xo[(size_t)(i0 + rr) * DM + na] = xa;
        a.xo[(size_t)(i0 + rr) * DM + nb] = xb;
      }
    }
  }
  __syncthreads();

  // ---- LN1-next (or LNf) -> Ab ----
  ln8(Xf, Ab, a.lns, a.lnb, t);
  __syncthreads();

  #pragma unroll
  for (int kc = 0; kc < 8; ++kc)
    af[kc] = *(const f16x8*)&Ab[lr][kc * 32 + lq * 8];

  // ---- stage 6: qkv next / pair projection ----
  if (!LAST) {
    const unsigned short* wp = a.wnp + (size_t)l * 8;
    f16x8 cur[8], nxt[8];
    #pragma unroll
    for (int kc = 0; kc < 8; ++kc)
      cur[kc] = *(const f16x8*)(wp + ((kc * 48 + w * 6) << 9));
    #pragma unroll
    for (int gi = 0; gi < 6; ++gi) {
      int g = w * 6 + gi;
      if (gi < 5) {
        #pragma unroll
        for (int kc = 0; kc < 8; ++kc)
          nxt[kc] = *(const f16x8*)(wp + ((kc * 48 + g + 1) << 9));
      }
      f32x4 ac = {0.f,0.f,0.f,0.f};
      #pragma unroll
      for (int kc = 0; kc < 8; ++kc)
        ac = __builtin_amdgcn_mfma_f32_16x16x32_f16(af[kc], cur[kc], ac, 0, 0, 0);
      if (lq < 2) {
        int n = g * 16 + lr;
        float* dst = n < 256 ? a.qo : (n < 512 ? a.ko : a.vo);
        int nn = n & 255;
        #pragma unroll
        for (int r = 0; r < 4; ++r)
          dst[(size_t)(i0 + lq * 4 + r) * DM + nn] = ac[r];
      }
      if (gi < 5) {
        #pragma unroll
        for (int kc = 0; kc < 8; ++kc) cur[kc] = nxt[kc];
      }
    }
  } else {
    const unsigned short* wp = a.wnp + (size_t)l * 8;
    f16x8 cur[8], nxt[8];
    #pragma unroll
    for (int kc = 0; kc < 8; ++kc)
      cur[kc] = *(const f16x8*)(wp + ((kc * 32 + w * 4) << 9));
    #pragma unroll
    for (int gi = 0; gi < 4; ++gi) {
      int g = w * 4 + gi;
      if (gi < 3) {
        #pragma unroll
        for (int kc = 0; kc < 8; ++kc)
          nxt[kc] = *(const f16x8*)(wp + ((kc * 32 + g + 1) << 9));
      }
      f32x4 ac = {0.f,0.f,0.f,0.f};
      #pragma unroll
      for (int kc = 0; kc < 8; ++kc)
        ac = __builtin_amdgcn_mfma_f32_16x16x32_f16(af[kc], cur[kc], ac, 0, 0, 0);
      if (lq < 2) {
        int n = g * 16 + lr;
        float* dst = n < 256 ? a.qo : a.ko;
        const float* bias = n < 256 ? a.nb0 : a.nb1;
        int nn = n & 255;
        float bv = bias[nn];
        #pragma unroll
        for (int r = 0; r < 4; ++r)
          dst[(size_t)(i0 + lq * 4 + r) * DM + nn] = ac[r] + bv;
      }
      if (gi < 3) {
        #pragma unroll
        for (int kc = 0; kc < 8; ++kc) cur[kc] = nxt[kc];
      }
    }
  }
}

// ---------------------------------------------------------------------------
// Fused pair head (validated): LDS-staged q/k, W1p reg-prefetch, packed cvt.
#define PAIR_SMEM 74864

__global__ __launch_bounds__(256, 2) void k_pair(
    const float* __restrict__ pq, const float* __restrict__ pk,
    const unsigned short* __restrict__ W1p, const float* __restrict__ RB,
    const float* __restrict__ w2, const float* __restrict__ b2,
    float* __restrict__ out) {
  extern __shared__ char smem[];
  float* qs   = (float*)smem;
  float* ks   = (float*)(smem + 4160);
  float* RB_s = (float*)(smem + 37440);
  float* racc = (float*)(smem + 73840);

  int t = threadIdx.x;
  int j0 = blockIdx.x * 32;
  int i0 = blockIdx.y * 4;
  int w = t >> 6, l = t & 63;
  int q4 = l >> 4, l15 = l & 15;
  int mwv = w & 1, nwv = w >> 1;

  {
    int row = t >> 6, c4 = (t & 63) * 4;
    *(float4*)(qs + row * 260 + c4) = *(const float4*)(pq + (size_t)(i0 + row) * DM + c4);
    #pragma unroll
    for (int r8 = 0; r8 < 8; ++r8) {
      int idx = t + r8 * 256;
      int kr = idx >> 6, kc4 = (idx & 63) * 4;
      *(float4*)(ks + kr * 260 + kc4) = *(const float4*)(pk + (size_t)(j0 + kr) * DM + kc4);
    }
    int ddmin = i0 - j0 + 736;
    for (int idx = t; idx < 35 * 64; idx += 256) {
      int lc = idx >> 6, c4b = (idx & 63) * 4;
      *(float4*)(RB_s + lc * 260 + c4b) =
          *(const float4*)(RB + (size_t)(ddmin + lc) * 256 + c4b);
    }
    racc[t] = 0.f;
  }
  __syncthreads();

  const unsigned short* Bp = W1p + (size_t)(nwv * 8) * 512 + (size_t)l * 8;
  const float* q0p = qs + (mwv * 2) * 260;
  const float* q1p = qs + (mwv * 2 + 1) * 260;
  const float* k0p = ks + l15 * 260;
  const float* k1p = ks + (16 + l15) * 260;

  f32x4 acc[4][8];
  #pragma unroll
  for (int aa = 0; aa < 4; ++aa)
    #pragma unroll
    for (int bb = 0; bb < 8; ++bb) acc[aa][bb] = (f32x4){0.f, 0.f, 0.f, 0.f};

  bf16x8 bcur[8];
  #pragma unroll
  for (int nt = 0; nt < 8; ++nt) bcur[nt] = *(const bf16x8*)(Bp + nt * 512);

  for (int kc = 0; kc < 8; ++kc) {
    bf16x8 bnxt[8];
    if (kc < 7) {
      const unsigned short* bbn = Bp + (size_t)(kc + 1) * 8192;
      #pragma unroll
      for (int nt = 0; nt < 8; ++nt) bnxt[nt] = *(const bf16x8*)(bbn + nt * 512);
    }
    int c = kc * 32 + q4 * 8;
    float4 qa0 = *(const float4*)(q0p + c), qa1 = *(const float4*)(q0p + c + 4);
    float4 qb0 = *(const float4*)(q1p + c), qb1 = *(const float4*)(q1p + c + 4);
    float4 ka0 = *(const float4*)(k0p + c), ka1 = *(const float4*)(k0p + c + 4);
    float4 kb0 = *(const float4*)(k1p + c), kb1 = *(const float4*)(k1p + c + 4);

    union { bf16x8 v; unsigned u[4]; } af[4];
    af[0].u[0] = pk2(qa0.x*ka0.x, qa0.y*ka0.y); af[0].u[1] = pk2(qa0.z*ka0.z, qa0.w*ka0.w);
    af[0].u[2] = pk2(qa1.x*ka1.x, qa1.y*ka1.y); af[0].u[3] = pk2(qa1.z*ka1.z, qa1.w*ka1.w);
    af[1].u[0] = pk2(qa0.x*kb0.x, qa0.y*kb0.y); af[1].u[1] = pk2(qa0.z*kb0.z, qa0.w*kb0.w);
    af[1].u[2] = pk2(qa1.x*kb1.x, qa1.y*kb1.y); af[1].u[3] = pk2(qa1.z*kb1.z, qa1.w*kb1.w);
    af[2].u[0] = pk2(qb0.x*ka0.x, qb0.y*ka0.y); af[2].u[1] = pk2(qb0.z*ka0.z, qb0.w*ka0.w);
    af[2].u[2] = pk2(qb1.x*ka1.x, qb1.y*ka1.y); af[2].u[3] = pk2(qb1.z*ka1.z, qb1.w*ka1.w);
    af[3].u[0] = pk2(qb0.x*kb0.x, qb0.y*kb0.y); af[3].u[1] = pk2(qb0.z*kb0.z, qb0.w*kb0.w);
    af[3].u[2] = pk2(qb1.x*kb1.x, qb1.y*kb1.y); af[3].u[3] = pk2(qb1.z*kb1.z, qb1.w*kb1.w);

    #pragma unroll
    for (int mt = 0; mt < 4; ++mt)
      #pragma unroll
      for (int nt = 0; nt < 8; ++nt)
        acc[mt][nt] = __builtin_amdgcn_mfma_f32_16x16x32_bf16(af[mt].v, bcur[nt], acc[mt][nt], 0, 0, 0);
    if (kc < 7) {
      #pragma unroll
      for (int nt = 0; nt < 8; ++nt) bcur[nt] = bnxt[nt];
    }
  }

  float w20[8], w21[8];
  #pragma unroll
  for (int nt = 0; nt < 8; ++nt) {
    int n = nwv * 128 + nt * 16 + l15;
    w20[nt] = w2[n * 2];
    w21[nt] = w2[n * 2 + 1];
  }
  #pragma unroll
  for (int mt = 0; mt < 4; ++mt) {
    #pragma unroll
    for (int reg = 0; reg < 4; ++reg) {
      int r = mwv * 64 + mt * 16 + q4 * 4 + reg;
      int lc = (r >> 5) - (r & 31) + 31;
      float o0 = 0.f, o1 = 0.f;
      #pragma unroll
      for (int nt = 0; nt < 8; ++nt) {
        int n = nwv * 128 + nt * 16 + l15;
        float T = acc[mt][nt][reg] + RB_s[lc * 260 + n];
        T = fmaxf(T, 0.f);
        o0 = fmaf(T, w20[nt], o0);
        o1 = fmaf(T, w21[nt], o1);
      }
      #pragma unroll
      for (int s = 1; s < 16; s <<= 1) {
        o0 += __shfl_xor(o0, s);
        o1 += __shfl_xor(o1, s);
      }
      if (l15 == 0) {
        atomicAdd(&racc[r * 2 + 0], o0);
        atomicAdd(&racc[r * 2 + 1], o1);
      }
    }
  }
  __syncthreads();
  {
    int r = t >> 1, oo = t & 1;
    out[((size_t)(i0 + (r >> 5)) * LSEQ + (j0 + (r & 31))) * 2 + oo] = racc[t] + b2[oo];
  }
}

// ---------------------------------------------------------------------------
extern "C" void kernel_launch(void* const* d_in, const int* in_sizes, int n_in,
                              void* d_out, int out_size, void* d_ws, size_t ws_size,
                              hipStream_t stream) {
  const int*   seq      = (const int*)  d_in[0];
  const float* tok_emb  = (const float*)d_in[1];
  const float* rp_emb   = (const float*)d_in[2];
  const float* wq       = (const float*)d_in[3];
  const float* wk       = (const float*)d_in[4];
  const float* wv       = (const float*)d_in[5];
  const float* wo       = (const float*)d_in[6];
  const float* ln1_s    = (const float*)d_in[7];
  const float* ln1_b    = (const float*)d_in[8];
  const float* ln2_s    = (const float*)d_in[9];
  const float* ln2_b    = (const float*)d_in[10];
  const float* ffn_w1   = (const float*)d_in[11];
  const float* ffn_b1   = (const float*)d_in[12];
  const float* ffn_w2   = (const float*)d_in[13];
  const float* ffn_b2   = (const float*)d_in[14];
  const float* lnf_s    = (const float*)d_in[15];
  const float* lnf_b    = (const float*)d_in[16];
  const float* pair_q_w = (const float*)d_in[17];
  const float* pair_q_b = (const float*)d_in[18];
  const float* pair_k_w = (const float*)d_in[19];
  const float* pair_k_b = (const float*)d_in[20];
  const float* pair_rp  = (const float*)d_in[21];
  const float* cls_w1   = (const float*)d_in[22];
  const float* cls_b1   = (const float*)d_in[23];
  const float* cls_w2   = (const float*)d_in[24];
  const float* cls_b2   = (const float*)d_in[25];
  float* out = (float*)d_out;

  char* ws = (char*)d_ws;
  float* xb0 = (float*)(ws + 0);
  float* xb1 = (float*)(ws + 786432);
  float* qb[2] = { (float*)(ws + 1572864), (float*)(ws + 3932160) };
  float* kb[2] = { (float*)(ws + 2359296), (float*)(ws + 4718592) };
  float* vb[2] = { (float*)(ws + 3145728), (float*)(ws + 5505024) };
  float* o   = (float*)(ws + 6291456);
  float* pq  = (float*)(ws + 7077888);
  float* pk  = (float*)(ws + 7864320);
  float* RB  = (float*)(ws + 8650752);
  unsigned short* W1p = (unsigned short*)(ws + 10223616);
  float* abias = (float*)(ws + 10354688);
  // packed fp16 MFMA weights
  unsigned short* Wop    = (unsigned short*)(ws + 10403840);  // 8 x 65536  x2B
  unsigned short* W1pk   = (unsigned short*)(ws + 11452416);  // 8 x 262144 x2B
  unsigned short* W2pk   = (unsigned short*)(ws + 15646720);  // 8 x 262144 x2B
  unsigned short* Wqkvp  = (unsigned short*)(ws + 19841024);  // 8 x 196608 x2B
  unsigned short* Wpairp = (unsigned short*)(ws + 22986752);  // 131072 x2B

  (void)in_sizes; (void)n_in; (void)out_size; (void)ws_size;

  hipFuncSetAttribute(reinterpret_cast<const void*>(k_pair),
                      hipFuncAttributeMaxDynamicSharedMemorySize, PAIR_SMEM);
  hipFuncSetAttribute(reinterpret_cast<const void*>(k_attn2),
                      hipFuncAttributeMaxDynamicSharedMemorySize, ATTN_SMEM);

  k_prep<<<3638, 256, 0, stream>>>(seq, tok_emb, rp_emb, wq, wk, wv, wo,
                                   ffn_w1, ffn_w2, ln1_s, ln1_b,
                                   pair_rp, cls_w1, cls_b1, pair_q_w, pair_k_w,
                                   xb0, qb[0], kb[0], vb[0], RB, W1p, abias,
                                   Wop, W1pk, W2pk, Wqkvp, Wpairp);

  for (int l = 0; l < NLAYER; ++l) {
    int pi = l & 1, po = pi ^ 1;
    float* xin  = (l & 1) ? xb1 : xb0;
    float* xout = (l & 1) ? xb0 : xb1;

    k_attn2<<<dim3(48, 8), 256, ATTN_SMEM, stream>>>(qb[pi], kb[pi], vb[pi], abias, o);

    TC a{};
    a.o = o; a.xin = xin; a.xo = xout;
    a.wop = Wop + ((size_t)l << 16);
    a.ln2s = ln2_s + l * DM; a.ln2b = ln2_b + l * DM;
    a.w1p = W1pk + ((size_t)l << 18); a.fb1 = ffn_b1 + (size_t)l * DFF;
    a.w2p = W2pk + ((size_t)l << 18); a.fb2 = ffn_b2 + (size_t)l * DM;
    if (l < NLAYER - 1) {
      a.wnp = Wqkvp + (size_t)(l + 1) * 196608;
      a.lns = ln1_s + (l + 1) * DM; a.lnb = ln1_b + (l + 1) * DM;
      a.qo = qb[po]; a.ko = kb[po]; a.vo = vb[po];
      k_tail3<0><<<96, 512, 0, stream>>>(a);
    } else {
      a.wnp = Wpairp;
      a.nb0 = pair_q_b; a.nb1 = pair_k_b;
      a.lns = lnf_s; a.lnb = lnf_b;
      a.qo = pq; a.ko = pk;
      k_tail3<1><<<96, 512, 0, stream>>>(a);
    }
  }

  k_pair<<<dim3(24, 192), 256, PAIR_SMEM, stream>>>(pq, pk, W1p, RB, cls_w2, cls_b2, out);
}

// Round 4
// 653.106 us; speedup vs baseline: 2.0849x; 1.0077x over previous
//
#include <hip/hip_runtime.h>
#include <hip/hip_bf16.h>
#include <stdint.h>

// ---------------------------------------------------------------------------
#define LSEQ 768
#define DM   256
#define NH   8
#define DK   32
#define DFF  1024
#define NLAYER 8
#define NDD  1535
// ---------------------------------------------------------------------------

typedef __attribute__((ext_vector_type(8))) short     bf16x8;
typedef __attribute__((ext_vector_type(8))) _Float16  f16x8;
typedef __attribute__((ext_vector_type(4))) float     f32x4;

__device__ __forceinline__ unsigned short f2bf(float f) {
  unsigned u = __float_as_uint(f);
  u += 0x7fffu + ((u >> 16) & 1u);       // RNE
  return (unsigned short)(u >> 16);
}
__device__ __forceinline__ unsigned short f2h(float f) {
  union { _Float16 h; unsigned short s; } c;
  c.h = (_Float16)f;                     // v_cvt_f16_f32 (RNE)
  return c.s;
}
__device__ __forceinline__ unsigned pk2(float a, float b) {
  __hip_bfloat162 h = __float22bfloat162_rn(make_float2(a, b));
  union { __hip_bfloat162 h; unsigned u; } c; c.h = h;
  return c.u;
}
__device__ __forceinline__ int bucket_of(int dd) {
  int rel = dd - 767;
  int ret = rel < 0 ? 32 : 0;
  int arp = rel < 0 ? -rel : rel;
  if (arp < 16) return ret + arp;
  const float lr = 2.772588722239781f;   // float(np.log(16))
  float val = logf((float)arp * 0.0625f) / lr * 16.0f;
  int vi = 16 + (int)val;
  return ret + (vi < 31 ? vi : 31);
}

// ---------------------------------------------------------------------------
// MFMA B-fragment packers: row-major [K][N] fp32 -> [K/32][N/16][lane][8] fp16
// (lane layout: n = g*16 + (lane&15), k = kc*32 + (lane>>4)*8 + e)
__device__ __forceinline__ void pack8h(unsigned short* dst, int id,
                                       const float* src, int N, int G) {
  int lane = (id >> 3) & 63;
  int rem = id >> 9;
  int g = rem % G, kc = rem / G;
  int kb = kc * 32 + ((lane >> 4) << 3);
  int n = g * 16 + (lane & 15);
  union { unsigned short s[8]; uint4 v; } U;
  #pragma unroll
  for (int e = 0; e < 8; ++e) U.s[e] = f2h(src[(size_t)(kb + e) * N + n]);
  *(uint4*)(dst + id) = U.v;
}

// N-concat of up to 3 [K][256] matrices (qkv: G=48, pair q/k: G=32)
__device__ __forceinline__ void pack8h_cat(unsigned short* dst, int id,
                                           const float* s0, const float* s1,
                                           const float* s2, int G) {
  int lane = (id >> 3) & 63;
  int rem = id >> 9;
  int g = rem % G, kc = rem / G;
  int kb = kc * 32 + ((lane >> 4) << 3);
  int n = g * 16 + (lane & 15);
  const float* sp = n < 256 ? s0 : (n < 512 ? s1 : s2);
  int nn = n & 255;
  union { unsigned short s[8]; uint4 v; } U;
  #pragma unroll
  for (int e = 0; e < 8; ++e) U.s[e] = f2h(sp[(size_t)(kb + e) * 256 + nn]);
  *(uint4*)(dst + id) = U.v;
}

// ---------------------------------------------------------------------------
// Legacy 64x64 GEMM tile (k_prep only; plain caching, gather variants).
// LDS from smc: As 2x32x68 @0, Bs @17408, stat @34816, red @35328 -> 37376.
template <int LN, int GR>
__device__ void gemm_tile(const float* gsrc, const int* seqIdx,
                          const float* B, const float* bias, float* C,
                          const float* lns, const float* lnb,
                          int M, int K, int N, int m0, int n0, char* smc) {
  float (*As)[32][68] = (float (*)[32][68])smc;
  float (*Bs)[32][68] = (float (*)[32][68])(smc + 17408);
  float (*stat)[2]    = (float (*)[2])(smc + 34816);
  float (*red)[8]     = (float (*)[8])(smc + 35328);

  int t = threadIdx.x;
  int arow = t >> 2, akq = (t & 3) * 8;
  int mg = m0 + arow;
  int mgc = mg < M ? mg : M - 1;
  const float* Ar = (GR == 1) ? (gsrc + (size_t)seqIdx[mgc] * K)
                              : (gsrc + (size_t)bucket_of(mgc) * K);
  float mean = 0.f, rstd = 0.f;
  if (LN) {
    int lq = t & 3;
    float s = 0.f, s2 = 0.f;
    const float* p = Ar + lq * 64;
    #pragma unroll
    for (int c = 0; c < 64; c += 4) {
      float4 v = *(const float4*)(p + c);
      s  += v.x + v.y + v.z + v.w;
      s2 += v.x * v.x + v.y * v.y + v.z * v.z + v.w * v.w;
    }
    red[arow][lq] = s; red[arow][lq + 4] = s2;
    __syncthreads();
    if (lq == 0) {
      float sm = red[arow][0] + red[arow][1] + red[arow][2] + red[arow][3];
      float sq = red[arow][4] + red[arow][5] + red[arow][6] + red[arow][7];
      float m = sm * (1.f / 256.f);
      float v = sq * (1.f / 256.f) - m * m;
      stat[arow][0] = m;
      stat[arow][1] = rsqrtf(v + 1e-5f);
    }
    __syncthreads();
    mean = stat[arow][0]; rstd = stat[arow][1];
  }

  int bkr = t >> 3, bn8 = (t & 7) * 8;
  int ty = t >> 4, tx = t & 15;
  float acc[4][4] = {};
  int nk = K >> 5;

  for (int kt = 0; kt < nk; ++kt) {
    int k0 = kt << 5;
    float4 a0 = *(const float4*)(Ar + k0 + akq);
    float4 a1 = *(const float4*)(Ar + k0 + akq + 4);
    if (LN) {
      float4 ls0 = *(const float4*)(lns + k0 + akq), ls1 = *(const float4*)(lns + k0 + akq + 4);
      float4 lb0 = *(const float4*)(lnb + k0 + akq), lb1 = *(const float4*)(lnb + k0 + akq + 4);
      a0.x=(a0.x-mean)*rstd*ls0.x+lb0.x; a0.y=(a0.y-mean)*rstd*ls0.y+lb0.y;
      a0.z=(a0.z-mean)*rstd*ls0.z+lb0.z; a0.w=(a0.w-mean)*rstd*ls0.w+lb0.w;
      a1.x=(a1.x-mean)*rstd*ls1.x+lb1.x; a1.y=(a1.y-mean)*rstd*ls1.y+lb1.y;
      a1.z=(a1.z-mean)*rstd*ls1.z+lb1.z; a1.w=(a1.w-mean)*rstd*ls1.w+lb1.w;
    }
    int cur = kt & 1;
    As[cur][akq+0][arow]=a0.x; As[cur][akq+1][arow]=a0.y; As[cur][akq+2][arow]=a0.z; As[cur][akq+3][arow]=a0.w;
    As[cur][akq+4][arow]=a1.x; As[cur][akq+5][arow]=a1.y; As[cur][akq+6][arow]=a1.z; As[cur][akq+7][arow]=a1.w;
    *(float4*)&Bs[cur][bkr][bn8] = *(const float4*)(B + (size_t)(k0 + bkr) * N + n0 + bn8);
    *(float4*)&Bs[cur][bkr][bn8+4] = *(const float4*)(B + (size_t)(k0 + bkr) * N + n0 + bn8 + 4);
    __syncthreads();
    #pragma unroll 8
    for (int kk = 0; kk < 32; ++kk) {
      float4 a = *(float4*)&As[cur][kk][ty * 4];
      float4 b = *(float4*)&Bs[cur][kk][tx * 4];
      acc[0][0]=fmaf(a.x,b.x,acc[0][0]); acc[0][1]=fmaf(a.x,b.y,acc[0][1]);
      acc[0][2]=fmaf(a.x,b.z,acc[0][2]); acc[0][3]=fmaf(a.x,b.w,acc[0][3]);
      acc[1][0]=fmaf(a.y,b.x,acc[1][0]); acc[1][1]=fmaf(a.y,b.y,acc[1][1]);
      acc[1][2]=fmaf(a.y,b.z,acc[1][2]); acc[1][3]=fmaf(a.y,b.w,acc[1][3]);
      acc[2][0]=fmaf(a.z,b.x,acc[2][0]); acc[2][1]=fmaf(a.z,b.y,acc[2][1]);
      acc[2][2]=fmaf(a.z,b.z,acc[2][2]); acc[2][3]=fmaf(a.z,b.w,acc[2][3]);
      acc[3][0]=fmaf(a.w,b.x,acc[3][0]); acc[3][1]=fmaf(a.w,b.y,acc[3][1]);
      acc[3][2]=fmaf(a.w,b.z,acc[3][2]); acc[3][3]=fmaf(a.w,b.w,acc[3][3]);
    }
    __syncthreads();
  }

  #pragma unroll
  for (int u = 0; u < 4; ++u) {
    int m = m0 + ty * 4 + u;
    if (m < M) {
      int n = n0 + tx * 4;
      float4 val = make_float4(acc[u][0], acc[u][1], acc[u][2], acc[u][3]);
      if (bias) {
        float4 bv = *(const float4*)(bias + n);
        val.x += bv.x; val.y += bv.y; val.z += bv.z; val.w += bv.w;
      }
      *(float4*)(C + (size_t)m * N + n) = val;
    }
  }
}

// ---------------------------------------------------------------------------
// Prep: RB gemm + qkv layer0 + embed + abias + W1p pack + fp16 weight packs.
__global__ __launch_bounds__(256, 2) void k_prep(
    const int* __restrict__ seq, const float* __restrict__ tok_emb,
    const float* __restrict__ rp_emb,
    const float* __restrict__ wq, const float* __restrict__ wk,
    const float* __restrict__ wv, const float* __restrict__ wo,
    const float* __restrict__ ffn_w1, const float* __restrict__ ffn_w2,
    const float* __restrict__ ln1s0, const float* __restrict__ ln1b0,
    const float* __restrict__ pair_rp, const float* __restrict__ cls_w1,
    const float* __restrict__ cls_b1,
    const float* __restrict__ pair_q_w, const float* __restrict__ pair_k_w,
    float* x0, float* q0, float* k0, float* v0, float* RB,
    unsigned short* W1p, float* abias,
    unsigned short* Wop, unsigned short* W1pk, unsigned short* W2pk,
    unsigned short* Wqkvp, unsigned short* Wpairp) {
  __shared__ __align__(16) char sm[37376];
  int b = blockIdx.x, t = threadIdx.x;
  if (b < 96) {
    int m0 = (b % 24) * 64, n0 = (b / 24) * 64;
    gemm_tile<0,2>(pair_rp, nullptr, cls_w1, cls_b1, RB,
                   nullptr, nullptr, NDD, 256, 256, m0, n0, sm);
  } else if (b < 240) {
    int u = b - 96;
    int n0g = (u % 12) * 64, m0 = (u / 12) * 64;
    int bi = n0g >> 8, n0 = n0g & 255;
    const float* B = bi == 0 ? wq : (bi == 1 ? wk : wv);
    float* C = bi == 0 ? q0 : (bi == 1 ? k0 : v0);
    gemm_tile<1,1>(tok_emb, seq, B, nullptr, C,
                   ln1s0, ln1b0, LSEQ, 256, 256, m0, n0, sm);
  } else if (b < 432) {
    int row = (b - 240) * 4 + (t >> 6), c = (t & 63) * 4;
    *(float4*)(x0 + (size_t)row * DM + c) =
        *(const float4*)(tok_emb + (size_t)seq[row] * DM + c);
  } else if (b < 438) {
    int dd = (b - 432) * 256 + t;
    if (dd < NDD) {
      int bk = bucket_of(dd);
      #pragma unroll
      for (int h = 0; h < NH; ++h) abias[dd * 8 + h] = rp_emb[bk * 8 + h];
    }
  } else if (b < 502) {
    int base = (b - 438) * 1024 + t * 4;
    #pragma unroll
    for (int uu = 0; uu < 4; ++uu) {
      int id = base + uu;
      int e = id & 7, lane = (id >> 3) & 63, g = (id >> 9) & 15, kc = id >> 13;
      int kg = kc * 32 + (lane >> 4) * 8 + e;
      int n  = g * 16 + (lane & 15);
      W1p[id] = f2bf(cls_w1[(size_t)kg * 256 + n]);
    }
  } else {
    // fp16 MFMA weight packing: 3136 blocks x 2048 elems
    int u = (b - 502) * 2048 + t * 8;
    if (u < 524288) {                       // wo: 8 x [256][256], G=16
      int layer = u >> 16, id = u & 65535;
      pack8h(Wop + ((size_t)layer << 16), id, wo + ((size_t)layer << 16), 256, 16);
    } else if (u < 2621440) {               // ffn_w1: 8 x [256][1024], G=64
      int v2 = u - 524288; int layer = v2 >> 18, id = v2 & 262143;
      pack8h(W1pk + ((size_t)layer << 18), id, ffn_w1 + ((size_t)layer << 18), 1024, 64);
    } else if (u < 4718592) {               // ffn_w2: 8 x [1024][256], G=16
      int v2 = u - 2621440; int layer = v2 >> 18, id = v2 & 262143;
      pack8h(W2pk + ((size_t)layer << 18), id, ffn_w2 + ((size_t)layer << 18), 256, 16);
    } else if (u < 6291456) {               // qkv concat: 8 x [256][768], G=48
      int v2 = u - 4718592; int layer = v2 / 196608, id = v2 - layer * 196608;
      pack8h_cat(Wqkvp + (size_t)layer * 196608, id,
                 wq + ((size_t)layer << 16), wk + ((size_t)layer << 16),
                 wv + ((size_t)layer << 16), 48);
    } else {                                // pair q/k concat: [256][512], G=32
      int id = u - 6291456;
      pack8h_cat(Wpairp, id, pair_q_w, pair_k_w, pair_k_w, 32);
    }
  }
}

// ---------------------------------------------------------------------------
// Attention (validated round 7): 16 q-rows x 1 head per block.
#define ATTN_SMEM 72960

__global__ __launch_bounds__(256, 2) void k_attn2(
    const float* __restrict__ q, const float* __restrict__ k,
    const float* __restrict__ v, const float* __restrict__ abias,
    float* __restrict__ o) {
  extern __shared__ char sm[];
  float* S  = (float*)sm;
  float* KV = (float*)(sm + 49664);
  float* QS = (float*)(sm + 66560);
  float* BS = (float*)(sm + 68672);
  float (*red)[16] = (float (*)[16])(sm + 71808);
  float* mrow = (float*)(sm + 72832);
  float* linv = (float*)(sm + 72896);

  int i0 = blockIdx.x * 16, h = blockIdx.y, hc = h * DK;
  int t = threadIdx.x;

  for (int u = t; u < 783; u += 256)
    BS[u] = abias[(size_t)(i0 + u) * 8 + h];
  {
    int r = t >> 4, c = t & 15;
    const float inv = 0.17677669529663687f;   // 1/sqrt(32)
    QS[r * 33 + c]      = q[(size_t)(i0 + r) * DM + hc + c] * inv;
    QS[r * 33 + c + 16] = q[(size_t)(i0 + r) * DM + hc + c + 16] * inv;
  }

  int kx = t & 31, ry = t >> 5;
  int key = t >> 1, half = t & 1;

  for (int cc = 0; cc < 6; ++cc) {
    const float* kp = k + (size_t)(cc * 128 + key) * DM + hc + half * 16;
    float4 L0 = *(const float4*)(kp);
    float4 L1 = *(const float4*)(kp + 4);
    float4 L2 = *(const float4*)(kp + 8);
    float4 L3 = *(const float4*)(kp + 12);
    __syncthreads();
    int cb = half * 16;
    KV[(cb+ 0)*132+key]=L0.x; KV[(cb+ 1)*132+key]=L0.y; KV[(cb+ 2)*132+key]=L0.z; KV[(cb+ 3)*132+key]=L0.w;
    KV[(cb+ 4)*132+key]=L1.x; KV[(cb+ 5)*132+key]=L1.y; KV[(cb+ 6)*132+key]=L1.z; KV[(cb+ 7)*132+key]=L1.w;
    KV[(cb+ 8)*132+key]=L2.x; KV[(cb+ 9)*132+key]=L2.y; KV[(cb+10)*132+key]=L2.z; KV[(cb+11)*132+key]=L2.w;
    KV[(cb+12)*132+key]=L3.x; KV[(cb+13)*132+key]=L3.y; KV[(cb+14)*132+key]=L3.z; KV[(cb+15)*132+key]=L3.w;
    __syncthreads();

    float s0x=0,s0y=0,s0z=0,s0w=0, s1x=0,s1y=0,s1z=0,s1w=0;
    #pragma unroll
    for (int kk = 0; kk < 32; ++kk) {
      float q0 = QS[(ry*2    )*33 + kk];
      float q1 = QS[(ry*2 + 1)*33 + kk];
      float4 kv4 = *(const float4*)&KV[kk*132 + kx*4];
      s0x = fmaf(q0, kv4.x, s0x); s0y = fmaf(q0, kv4.y, s0y);
      s0z = fmaf(q0, kv4.z, s0z); s0w = fmaf(q0, kv4.w, s0w);
      s1x = fmaf(q1, kv4.x, s1x); s1y = fmaf(q1, kv4.y, s1y);
      s1z = fmaf(q1, kv4.z, s1z); s1w = fmaf(q1, kv4.w, s1w);
    }
    int jb = cc * 128 + kx * 4;
    int r0 = ry * 2, r1 = r0 + 1;
    S[r0*776 + jb+0] = s0x + BS[r0 + 767 - (jb+0)];
    S[r0*776 + jb+1] = s0y + BS[r0 + 767 - (jb+1)];
    S[r0*776 + jb+2] = s0z + BS[r0 + 767 - (jb+2)];
    S[r0*776 + jb+3] = s0w + BS[r0 + 767 - (jb+3)];
    S[r1*776 + jb+0] = s1x + BS[r1 + 767 - (jb+0)];
    S[r1*776 + jb+1] = s1y + BS[r1 + 767 - (jb+1)];
    S[r1*776 + jb+2] = s1z + BS[r1 + 767 - (jb+2)];
    S[r1*776 + jb+3] = s1w + BS[r1 + 767 - (jb+3)];
  }
  __syncthreads();

  {
    int ti = t >> 4, tj = t & 15;
    float mx = -1e30f;
    for (int jc = 0; jc < 48; ++jc)
      mx = fmaxf(mx, S[ti*776 + jc*16 + tj]);
    red[ti][tj] = mx;
    __syncthreads();
    if (tj == 0) {
      float m2 = red[ti][0];
      #pragma unroll
      for (int u = 1; u < 16; ++u) m2 = fmaxf(m2, red[ti][u]);
      mrow[ti] = m2;
    }
    __syncthreads();
    float m2 = mrow[ti];
    float sum = 0.f;
    for (int jc = 0; jc < 48; ++jc) {
      int j = jc*16 + tj;
      float e = __expf(S[ti*776 + j] - m2);
      S[ti*776 + j] = e;
      sum += e;
    }
    red[ti][tj] = sum;
    __syncthreads();
    if (tj == 0) {
      float s2 = 0.f;
      #pragma unroll
      for (int u = 0; u < 16; ++u) s2 += red[ti][u];
      linv[ti] = 1.f / s2;
    }
  }

  int cp = t & 15, jg = t >> 4;
  int c0 = cp * 2, c1 = c0 + 1;
  float oc0[16] = {}, oc1[16] = {};
  for (int cc = 0; cc < 6; ++cc) {
    const float* vp = v + (size_t)(cc * 128 + key) * DM + hc + half * 16;
    float4 L0 = *(const float4*)(vp);
    float4 L1 = *(const float4*)(vp + 4);
    float4 L2 = *(const float4*)(vp + 8);
    float4 L3 = *(const float4*)(vp + 12);
    __syncthreads();
    int cb = half * 16;
    KV[(cb+ 0)*132+key]=L0.x; KV[(cb+ 1)*132+key]=L0.y; KV[(cb+ 2)*132+key]=L0.z; KV[(cb+ 3)*132+key]=L0.w;
    KV[(cb+ 4)*132+key]=L1.x; KV[(cb+ 5)*132+key]=L1.y; KV[(cb+ 6)*132+key]=L1.z; KV[(cb+ 7)*132+key]=L1.w;
    KV[(cb+ 8)*132+key]=L2.x; KV[(cb+ 9)*132+key]=L2.y; KV[(cb+10)*132+key]=L2.z; KV[(cb+11)*132+key]=L2.w;
    KV[(cb+12)*132+key]=L3.x; KV[(cb+13)*132+key]=L3.y; KV[(cb+14)*132+key]=L3.z; KV[(cb+15)*132+key]=L3.w;
    __syncthreads();

    #pragma unroll
    for (int jj2 = 0; jj2 < 2; ++jj2) {
      int jb = jg * 8 + jj2 * 4;
      float4 vA = *(const float4*)&KV[c0*132 + jb];
      float4 vB = *(const float4*)&KV[c1*132 + jb];
      #pragma unroll
      for (int r = 0; r < 16; ++r) {
        float4 sv = *(const float4*)&S[r*776 + cc*128 + jb];
        oc0[r] += sv.x*vA.x + sv.y*vA.y + sv.z*vA.z + sv.w*vA.w;
        oc1[r] += sv.x*vB.x + sv.y*vB.y + sv.z*vB.z + sv.w*vB.w;
      }
    }
  }

  #pragma unroll
  for (int h2 = 0; h2 < 2; ++h2) {
    __syncthreads();
    #pragma unroll
    for (int r = 0; r < 8; ++r) {
      KV[(jg*8 + r)*32 + c0] = oc0[h2*8 + r];
      KV[(jg*8 + r)*32 + c1] = oc1[h2*8 + r];
    }
    __syncthreads();
    int r = t >> 5, c = t & 31;
    float s = 0.f;
    #pragma unroll
    for (int jgg = 0; jgg < 16; ++jgg) s += KV[(jgg*8 + r)*32 + c];
    o[(size_t)(i0 + h2*8 + r) * DM + hc + c] = s * linv[h2*8 + r];
  }
}

// ---------------------------------------------------------------------------
// Column-parallel fp16-MFMA layer tail, 3 kernels. All grids (48, 4), 256 thr,
// 16 rows/block (full MFMA M). LN row-dependencies handled by cheap dup-compute.

// k_t1: X1 = xin + O@Wo (dup x4; by==0 stores X1); LN2; ffn1 chunk + gelu -> F
__global__ __launch_bounds__(256, 2) void k_t1(
    const float* __restrict__ o, const float* __restrict__ xin,
    const unsigned short* __restrict__ wop,
    const float* __restrict__ ln2s, const float* __restrict__ ln2b,
    const unsigned short* __restrict__ w1p, const float* __restrict__ fb1,
    float* __restrict__ x1, unsigned short* __restrict__ Fg) {
  __shared__ __align__(16) float    Xf[16][260];
  __shared__ __align__(16) _Float16 Ab[16][264];
  int t = threadIdx.x;
  int i0 = blockIdx.x * 16;
  int by = blockIdx.y;
  int w = t >> 6, l = t & 63;
  int lr = l & 15, lq = l >> 4;

  // stage 0: O -> Ab (fp16), xin -> Xf  (coalesced: 16 lanes x float4)
  {
    int r = t >> 4, j = t & 15;
    #pragma unroll
    for (int q = 0; q < 4; ++q) {
      int c = j * 4 + q * 64;
      float4 v = *(const float4*)(o + (size_t)(i0 + r) * DM + c);
      union { _Float16 h[4]; uint2 u; } cv;
      cv.h[0] = (_Float16)v.x; cv.h[1] = (_Float16)v.y;
      cv.h[2] = (_Float16)v.z; cv.h[3] = (_Float16)v.w;
      *(uint2*)&Ab[r][c] = cv.u;
      *(float4*)&Xf[r][c] = *(const float4*)(xin + (size_t)(i0 + r) * DM + c);
    }
  }
  __syncthreads();

  f16x8 af[8];
  #pragma unroll
  for (int kc = 0; kc < 8; ++kc)
    af[kc] = *(const f16x8*)&Ab[lr][kc * 32 + lq * 8];

  // wo: wave w owns g = w*4..w*4+3 (full N=256, dup across by)
  {
    const unsigned short* wp = wop + (size_t)l * 8;
    #pragma unroll
    for (int gi = 0; gi < 4; ++gi) {
      int g = w * 4 + gi;
      f32x4 ac = {0.f, 0.f, 0.f, 0.f};
      #pragma unroll
      for (int kc = 0; kc < 8; ++kc) {
        f16x8 bb = *(const f16x8*)(wp + ((kc * 16 + g) << 9));
        ac = __builtin_amdgcn_mfma_f32_16x16x32_f16(af[kc], bb, ac, 0, 0, 0);
      }
      int n = g * 16 + lr;
      #pragma unroll
      for (int r = 0; r < 4; ++r)
        Xf[lq * 4 + r][n] += ac[r];
    }
  }
  __syncthreads();

  // store X1 (by==0 only)
  if (by == 0) {
    int r = t >> 4, j = t & 15;
    #pragma unroll
    for (int q = 0; q < 4; ++q) {
      int c = j * 4 + q * 64;
      *(float4*)(x1 + (size_t)(i0 + r) * DM + c) = *(const float4*)&Xf[r][c];
    }
  }

  // LN2 -> Ab (16 threads/row, 16-lane shuffle reduce)
  {
    int r = t >> 4, j = t & 15;
    int c0 = j * 16;
    float xv[16]; float s1 = 0.f, s2 = 0.f;
    #pragma unroll
    for (int u = 0; u < 16; ++u) {
      xv[u] = Xf[r][c0 + u];
      s1 += xv[u]; s2 += xv[u] * xv[u];
    }
    #pragma unroll
    for (int m = 1; m < 16; m <<= 1) {
      s1 += __shfl_xor(s1, m);
      s2 += __shfl_xor(s2, m);
    }
    float mean = s1 * (1.f / 256.f);
    float var  = s2 * (1.f / 256.f) - mean * mean;
    float rs = rsqrtf(var + 1e-5f);
    #pragma unroll
    for (int p = 0; p < 4; ++p) {
      union { _Float16 h[4]; uint2 u; } cv;
      #pragma unroll
      for (int e = 0; e < 4; ++e) {
        int c = c0 + p * 4 + e;
        cv.h[e] = (_Float16)((xv[p * 4 + e] - mean) * rs * ln2s[c] + ln2b[c]);
      }
      *(uint2*)&Ab[r][c0 + p * 4] = cv.u;
    }
  }
  __syncthreads();

  #pragma unroll
  for (int kc = 0; kc < 8; ++kc)
    af[kc] = *(const f16x8*)&Ab[lr][kc * 32 + lq * 8];

  // ffn1 chunk (g = by*16 + w*4 + gi) + gelu -> F (fp16, global)
  {
    const unsigned short* wp = w1p + (size_t)l * 8;
    #pragma unroll
    for (int gi = 0; gi < 4; ++gi) {
      int g = by * 16 + w * 4 + gi;
      f32x4 ac = {0.f, 0.f, 0.f, 0.f};
      #pragma unroll
      for (int kc = 0; kc < 8; ++kc) {
        f16x8 bb = *(const f16x8*)(wp + ((kc * 64 + g) << 9));
        ac = __builtin_amdgcn_mfma_f32_16x16x32_f16(af[kc], bb, ac, 0, 0, 0);
      }
      int n = g * 16 + lr;
      float b1 = fb1[n];
      #pragma unroll
      for (int r = 0; r < 4; ++r) {
        float v = ac[r] + b1;
        v = 0.5f * v * (1.f + erff(v * 0.70710678118654752f));
        Fg[(size_t)(i0 + lq * 4 + r) * DFF + n] = f2h(v);
      }
    }
  }
}

// k_t2: X2 = X1 + F@W2 + b2 (64-col chunk, K=1024 staged in LDS)
__global__ __launch_bounds__(256, 2) void k_t2(
    const unsigned short* __restrict__ Fg, const float* __restrict__ x1,
    const unsigned short* __restrict__ w2p, const float* __restrict__ fb2,
    float* __restrict__ x2) {
  __shared__ __align__(16) _Float16 Fs[16][1032];
  int t = threadIdx.x;
  int i0 = blockIdx.x * 16;
  int by = blockIdx.y;
  int w = t >> 6, l = t & 63;
  int lr = l & 15, lq = l >> 4;

  // stage F rows (coalesced: 16 lanes x uint4)
  {
    int r = t >> 4, j = t & 15;
    #pragma unroll
    for (int q = 0; q < 8; ++q) {
      int c = j * 8 + q * 128;
      *(uint4*)&Fs[r][c] = *(const uint4*)(Fg + (size_t)(i0 + r) * DFF + c);
    }
  }
  __syncthreads();

  int g = by * 4 + w;
  const unsigned short* wp = w2p + (size_t)l * 8;
  f32x4 ac0 = {0.f, 0.f, 0.f, 0.f}, ac1 = {0.f, 0.f, 0.f, 0.f};
  #pragma unroll
  for (int kc = 0; kc < 32; kc += 2) {
    f16x8 fa0 = *(const f16x8*)&Fs[lr][kc * 32 + lq * 8];
    f16x8 bb0 = *(const f16x8*)(wp + ((kc * 16 + g) << 9));
    ac0 = __builtin_amdgcn_mfma_f32_16x16x32_f16(fa0, bb0, ac0, 0, 0, 0);
    f16x8 fa1 = *(const f16x8*)&Fs[lr][(kc + 1) * 32 + lq * 8];
    f16x8 bb1 = *(const f16x8*)(wp + (((kc + 1) * 16 + g) << 9));
    ac1 = __builtin_amdgcn_mfma_f32_16x16x32_f16(fa1, bb1, ac1, 0, 0, 0);
  }
  int n = g * 16 + lr;
  float b2v = fb2[n];
  #pragma unroll
  for (int r = 0; r < 4; ++r) {
    int row = i0 + lq * 4 + r;
    x2[(size_t)row * DM + n] =
        x1[(size_t)row * DM + n] + ac0[r] + ac1[r] + b2v;
  }
}

// k_t3: LN1next/LNf (dup x4) + qkv chunk (or pair projection)
template <int LAST>
__global__ __launch_bounds__(256, 2) void k_t3(
    const float* __restrict__ x2,
    const float* __restrict__ lns, const float* __restrict__ lnb,
    const unsigned short* __restrict__ wnp,
    const float* __restrict__ nb0, const float* __restrict__ nb1,
    float* __restrict__ qo, float* __restrict__ ko, float* __restrict__ vo) {
  __shared__ __align__(16) _Float16 Ab[16][264];
  int t = threadIdx.x;
  int i0 = blockIdx.x * 16;
  int by = blockIdx.y;
  int w = t >> 6, l = t & 63;
  int lr = l & 15, lq = l >> 4;

  // load X2 rows + LN -> Ab
  {
    int r = t >> 4, j = t & 15;
    int c0 = j * 16;
    const float* xp = x2 + (size_t)(i0 + r) * DM + c0;
    float xv[16]; float s1 = 0.f, s2 = 0.f;
    #pragma unroll
    for (int u = 0; u < 16; u += 4) {
      float4 v = *(const float4*)(xp + u);
      xv[u] = v.x; xv[u+1] = v.y; xv[u+2] = v.z; xv[u+3] = v.w;
      s1 += v.x + v.y + v.z + v.w;
      s2 += v.x*v.x + v.y*v.y + v.z*v.z + v.w*v.w;
    }
    #pragma unroll
    for (int m = 1; m < 16; m <<= 1) {
      s1 += __shfl_xor(s1, m);
      s2 += __shfl_xor(s2, m);
    }
    float mean = s1 * (1.f / 256.f);
    float var  = s2 * (1.f / 256.f) - mean * mean;
    float rs = rsqrtf(var + 1e-5f);
    #pragma unroll
    for (int p = 0; p < 4; ++p) {
      union { _Float16 h[4]; uint2 u; } cv;
      #pragma unroll
      for (int e = 0; e < 4; ++e) {
        int c = c0 + p * 4 + e;
        cv.h[e] = (_Float16)((xv[p * 4 + e] - mean) * rs * lns[c] + lnb[c]);
      }
      *(uint2*)&Ab[r][c0 + p * 4] = cv.u;
    }
  }
  __syncthreads();

  f16x8 af[8];
  #pragma unroll
  for (int kc = 0; kc < 8; ++kc)
    af[kc] = *(const f16x8*)&Ab[lr][kc * 32 + lq * 8];

  const unsigned short* wp = wnp + (size_t)l * 8;
  if (!LAST) {
    // qkv: G=48, chunk 12 g, 3 g/wave
    #pragma unroll
    for (int gi = 0; gi < 3; ++gi) {
      int g = by * 12 + w * 3 + gi;
      f32x4 ac = {0.f, 0.f, 0.f, 0.f};
      #pragma unroll
      for (int kc = 0; kc < 8; ++kc) {
        f16x8 bb = *(const f16x8*)(wp + ((kc * 48 + g) << 9));
        ac = __builtin_amdgcn_mfma_f32_16x16x32_f16(af[kc], bb, ac, 0, 0, 0);
      }
      int n = g * 16 + lr;
      float* dst = n < 256 ? qo : (n < 512 ? ko : vo);
      int nn = n & 255;
      #pragma unroll
      for (int r = 0; r < 4; ++r)
        dst[(size_t)(i0 + lq * 4 + r) * DM + nn] = ac[r];
    }
  } else {
    // pair proj: G=32, chunk 8 g, 2 g/wave
    #pragma unroll
    for (int gi = 0; gi < 2; ++gi) {
      int g = by * 8 + w * 2 + gi;
      f32x4 ac = {0.f, 0.f, 0.f, 0.f};
      #pragma unroll
      for (int kc = 0; kc < 8; ++kc) {
        f16x8 bb = *(const f16x8*)(wp + ((kc * 32 + g) << 9));
        ac = __builtin_amdgcn_mfma_f32_16x16x32_f16(af[kc], bb, ac, 0, 0, 0);
      }
      int n = g * 16 + lr;
      float* dst = n < 256 ? qo : ko;
      const float* bias = n < 256 ? nb0 : nb1;
      int nn = n & 255;
      float bv = bias[nn];
      #pragma unroll
      for (int r = 0; r < 4; ++r)
        dst[(size_t)(i0 + lq * 4 + r) * DM + nn] = ac[r] + bv;
    }
  }
}

// ---------------------------------------------------------------------------
// Fused pair head (validated): LDS-staged q/k, W1p reg-prefetch, packed cvt.
#define PAIR_SMEM 74864

__global__ __launch_bounds__(256, 2) void k_pair(
    const float* __restrict__ pq, const float* __restrict__ pk,
    const unsigned short* __restrict__ W1p, const float* __restrict__ RB,
    const float* __restrict__ w2, const float* __restrict__ b2,
    float* __restrict__ out) {
  extern __shared__ char smem[];
  float* qs   = (float*)smem;
  float* ks   = (float*)(smem + 4160);
  float* RB_s = (float*)(smem + 37440);
  float* racc = (float*)(smem + 73840);

  int t = threadIdx.x;
  int j0 = blockIdx.x * 32;
  int i0 = blockIdx.y * 4;
  int w = t >> 6, l = t & 63;
  int q4 = l >> 4, l15 = l & 15;
  int mwv = w & 1, nwv = w >> 1;

  {
    int row = t >> 6, c4 = (t & 63) * 4;
    *(float4*)(qs + row * 260 + c4) = *(const float4*)(pq + (size_t)(i0 + row) * DM + c4);
    #pragma unroll
    for (int r8 = 0; r8 < 8; ++r8) {
      int idx = t + r8 * 256;
      int kr = idx >> 6, kc4 = (idx & 63) * 4;
      *(float4*)(ks + kr * 260 + kc4) = *(const float4*)(pk + (size_t)(j0 + kr) * DM + kc4);
    }
    int ddmin = i0 - j0 + 736;
    for (int idx = t; idx < 35 * 64; idx += 256) {
      int lc = idx >> 6, c4b = (idx & 63) * 4;
      *(float4*)(RB_s + lc * 260 + c4b) =
          *(const float4*)(RB + (size_t)(ddmin + lc) * 256 + c4b);
    }
    racc[t] = 0.f;
  }
  __syncthreads();

  const unsigned short* Bp = W1p + (size_t)(nwv * 8) * 512 + (size_t)l * 8;
  const float* q0p = qs + (mwv * 2) * 260;
  const float* q1p = qs + (mwv * 2 + 1) * 260;
  const float* k0p = ks + l15 * 260;
  const float* k1p = ks + (16 + l15) * 260;

  f32x4 acc[4][8];
  #pragma unroll
  for (int aa = 0; aa < 4; ++aa)
    #pragma unroll
    for (int bb = 0; bb < 8; ++bb) acc[aa][bb] = (f32x4){0.f, 0.f, 0.f, 0.f};

  bf16x8 bcur[8];
  #pragma unroll
  for (int nt = 0; nt < 8; ++nt) bcur[nt] = *(const bf16x8*)(Bp + nt * 512);

  for (int kc = 0; kc < 8; ++kc) {
    bf16x8 bnxt[8];
    if (kc < 7) {
      const unsigned short* bbn = Bp + (size_t)(kc + 1) * 8192;
      #pragma unroll
      for (int nt = 0; nt < 8; ++nt) bnxt[nt] = *(const bf16x8*)(bbn + nt * 512);
    }
    int c = kc * 32 + q4 * 8;
    float4 qa0 = *(const float4*)(q0p + c), qa1 = *(const float4*)(q0p + c + 4);
    float4 qb0 = *(const float4*)(q1p + c), qb1 = *(const float4*)(q1p + c + 4);
    float4 ka0 = *(const float4*)(k0p + c), ka1 = *(const float4*)(k0p + c + 4);
    float4 kb0 = *(const float4*)(k1p + c), kb1 = *(const float4*)(k1p + c + 4);

    union { bf16x8 v; unsigned u[4]; } af[4];
    af[0].u[0] = pk2(qa0.x*ka0.x, qa0.y*ka0.y); af[0].u[1] = pk2(qa0.z*ka0.z, qa0.w*ka0.w);
    af[0].u[2] = pk2(qa1.x*ka1.x, qa1.y*ka1.y); af[0].u[3] = pk2(qa1.z*ka1.z, qa1.w*ka1.w);
    af[1].u[0] = pk2(qa0.x*kb0.x, qa0.y*kb0.y); af[1].u[1] = pk2(qa0.z*kb0.z, qa0.w*kb0.w);
    af[1].u[2] = pk2(qa1.x*kb1.x, qa1.y*kb1.y); af[1].u[3] = pk2(qa1.z*kb1.z, qa1.w*kb1.w);
    af[2].u[0] = pk2(qb0.x*ka0.x, qb0.y*ka0.y); af[2].u[1] = pk2(qb0.z*ka0.z, qb0.w*ka0.w);
    af[2].u[2] = pk2(qb1.x*ka1.x, qb1.y*ka1.y); af[2].u[3] = pk2(qb1.z*ka1.z, qb1.w*ka1.w);
    af[3].u[0] = pk2(qb0.x*kb0.x, qb0.y*kb0.y); af[3].u[1] = pk2(qb0.z*kb0.z, qb0.w*kb0.w);
    af[3].u[2] = pk2(qb1.x*kb1.x, qb1.y*kb1.y); af[3].u[3] = pk2(qb1.z*kb1.z, qb1.w*kb1.w);

    #pragma unroll
    for (int mt = 0; mt < 4; ++mt)
      #pragma unroll
      for (int nt = 0; nt < 8; ++nt)
        acc[mt][nt] = __builtin_amdgcn_mfma_f32_16x16x32_bf16(af[mt].v, bcur[nt], acc[mt][nt], 0, 0, 0);
    if (kc < 7) {
      #pragma unroll
      for (int nt = 0; nt < 8; ++nt) bcur[nt] = bnxt[nt];
    }
  }

  float w20[8], w21[8];
  #pragma unroll
  for (int nt = 0; nt < 8; ++nt) {
    int n = nwv * 128 + nt * 16 + l15;
    w20[nt] = w2[n * 2];
    w21[nt] = w2[n * 2 + 1];
  }
  #pragma unroll
  for (int mt = 0; mt < 4; ++mt) {
    #pragma unroll
    for (int reg = 0; reg < 4; ++reg) {
      int r = mwv * 64 + mt * 16 + q4 * 4 + reg;
      int lc = (r >> 5) - (r & 31) + 31;
      float o0 = 0.f, o1 = 0.f;
      #pragma unroll
      for (int nt = 0; nt < 8; ++nt) {
        int n = nwv * 128 + nt * 16 + l15;
        float T = acc[mt][nt][reg] + RB_s[lc * 260 + n];
        T = fmaxf(T, 0.f);
        o0 = fmaf(T, w20[nt], o0);
        o1 = fmaf(T, w21[nt], o1);
      }
      #pragma unroll
      for (int s = 1; s < 16; s <<= 1) {
        o0 += __shfl_xor(o0, s);
        o1 += __shfl_xor(o1, s);
      }
      if (l15 == 0) {
        atomicAdd(&racc[r * 2 + 0], o0);
        atomicAdd(&racc[r * 2 + 1], o1);
      }
    }
  }
  __syncthreads();
  {
    int r = t >> 1, oo = t & 1;
    out[((size_t)(i0 + (r >> 5)) * LSEQ + (j0 + (r & 31))) * 2 + oo] = racc[t] + b2[oo];
  }
}

// ---------------------------------------------------------------------------
extern "C" void kernel_launch(void* const* d_in, const int* in_sizes, int n_in,
                              void* d_out, int out_size, void* d_ws, size_t ws_size,
                              hipStream_t stream) {
  const int*   seq      = (const int*)  d_in[0];
  const float* tok_emb  = (const float*)d_in[1];
  const float* rp_emb   = (const float*)d_in[2];
  const float* wq       = (const float*)d_in[3];
  const float* wk       = (const float*)d_in[4];
  const float* wv       = (const float*)d_in[5];
  const float* wo       = (const float*)d_in[6];
  const float* ln1_s    = (const float*)d_in[7];
  const float* ln1_b    = (const float*)d_in[8];
  const float* ln2_s    = (const float*)d_in[9];
  const float* ln2_b    = (const float*)d_in[10];
  const float* ffn_w1   = (const float*)d_in[11];
  const float* ffn_b1   = (const float*)d_in[12];
  const float* ffn_w2   = (const float*)d_in[13];
  const float* ffn_b2   = (const float*)d_in[14];
  const float* lnf_s    = (const float*)d_in[15];
  const float* lnf_b    = (const float*)d_in[16];
  const float* pair_q_w = (const float*)d_in[17];
  const float* pair_q_b = (const float*)d_in[18];
  const float* pair_k_w = (const float*)d_in[19];
  const float* pair_k_b = (const float*)d_in[20];
  const float* pair_rp  = (const float*)d_in[21];
  const float* cls_w1   = (const float*)d_in[22];
  const float* cls_b1   = (const float*)d_in[23];
  const float* cls_w2   = (const float*)d_in[24];
  const float* cls_b2   = (const float*)d_in[25];
  float* out = (float*)d_out;

  char* ws = (char*)d_ws;
  float* xb0 = (float*)(ws + 0);
  float* xb1 = (float*)(ws + 786432);
  float* qb[2] = { (float*)(ws + 1572864), (float*)(ws + 3932160) };
  float* kb[2] = { (float*)(ws + 2359296), (float*)(ws + 4718592) };
  float* vb[2] = { (float*)(ws + 3145728), (float*)(ws + 5505024) };
  float* o   = (float*)(ws + 6291456);
  float* pq  = (float*)(ws + 7077888);
  float* pk  = (float*)(ws + 7864320);
  float* RB  = (float*)(ws + 8650752);
  unsigned short* W1p = (unsigned short*)(ws + 10223616);
  float* abias = (float*)(ws + 10354688);
  // packed fp16 MFMA weights
  unsigned short* Wop    = (unsigned short*)(ws + 10403840);  // 8 x 65536  x2B
  unsigned short* W1pk   = (unsigned short*)(ws + 11452416);  // 8 x 262144 x2B
  unsigned short* W2pk   = (unsigned short*)(ws + 15646720);  // 8 x 262144 x2B
  unsigned short* Wqkvp  = (unsigned short*)(ws + 19841024);  // 8 x 196608 x2B
  unsigned short* Wpairp = (unsigned short*)(ws + 22986752);  // 131072 x2B
  unsigned short* Fg     = (unsigned short*)(ws + 23248896);  // 768x1024 fp16
  float* x1buf           = (float*)(ws + 24821760);           // 768x256 f32

  (void)in_sizes; (void)n_in; (void)out_size; (void)ws_size;

  hipFuncSetAttribute(reinterpret_cast<const void*>(k_pair),
                      hipFuncAttributeMaxDynamicSharedMemorySize, PAIR_SMEM);
  hipFuncSetAttribute(reinterpret_cast<const void*>(k_attn2),
                      hipFuncAttributeMaxDynamicSharedMemorySize, ATTN_SMEM);

  k_prep<<<3638, 256, 0, stream>>>(seq, tok_emb, rp_emb, wq, wk, wv, wo,
                                   ffn_w1, ffn_w2, ln1_s, ln1_b,
                                   pair_rp, cls_w1, cls_b1, pair_q_w, pair_k_w,
                                   xb0, qb[0], kb[0], vb[0], RB, W1p, abias,
                                   Wop, W1pk, W2pk, Wqkvp, Wpairp);

  for (int l = 0; l < NLAYER; ++l) {
    int pi = l & 1, po = pi ^ 1;
    float* xin  = (l & 1) ? xb1 : xb0;
    float* xout = (l & 1) ? xb0 : xb1;

    k_attn2<<<dim3(48, 8), 256, ATTN_SMEM, stream>>>(qb[pi], kb[pi], vb[pi], abias, o);

    k_t1<<<dim3(48, 4), 256, 0, stream>>>(
        o, xin, Wop + ((size_t)l << 16),
        ln2_s + l * DM, ln2_b + l * DM,
        W1pk + ((size_t)l << 18), ffn_b1 + (size_t)l * DFF,
        x1buf, Fg);

    k_t2<<<dim3(48, 4), 256, 0, stream>>>(
        Fg, x1buf, W2pk + ((size_t)l << 18), ffn_b2 + (size_t)l * DM, xout);

    if (l < NLAYER - 1) {
      k_t3<0><<<dim3(48, 4), 256, 0, stream>>>(
          xout, ln1_s + (l + 1) * DM, ln1_b + (l + 1) * DM,
          Wqkvp + (size_t)(l + 1) * 196608, nullptr, nullptr,
          qb[po], kb[po], vb[po]);
    } else {
      k_t3<1><<<dim3(48, 4), 256, 0, stream>>>(
          xout, lnf_s, lnf_b, Wpairp, pair_q_b, pair_k_b,
          pq, pk, nullptr);
    }
  }

  k_pair<<<dim3(24, 192), 256, PAIR_SMEM, stream>>>(pq, pk, W1p, RB, cls_w2, cls_b2, out);
}